// Round 2
// baseline (1363.487 us; speedup 1.0000x reference)
//
#include <hip/hip_runtime.h>
#include <hip/hip_bf16.h>

#define HID 2048
#define NH 16
#define HD 128
#define INTER 8192
#define SS 2048

typedef unsigned short u16;
typedef __attribute__((ext_vector_type(8))) short short8;
typedef __attribute__((ext_vector_type(4))) float f32x4;

__device__ __forceinline__ float bf2f(u16 u) {
    unsigned v = ((unsigned)u) << 16; float f; __builtin_memcpy(&f, &v, 4); return f;
}
__device__ __forceinline__ u16 f2bf(float f) {
    unsigned u; __builtin_memcpy(&u, &f, 4);
    u = u + 0x7FFFu + ((u >> 16) & 1u);   // RNE
    return (u16)(u >> 16);
}

typedef const __attribute__((address_space(1))) void* gas_t;
typedef __attribute__((address_space(3))) void* las_t;
__device__ __forceinline__ void gll16(const void* g, void* l) {
    __builtin_amdgcn_global_load_lds((gas_t)g, (las_t)l, 16, 0, 0);
}

// ---------------- elementwise / prep kernels ----------------

__global__ __launch_bounds__(256) void cast_f32_bf16_kernel(
    const float* __restrict__ src, u16* __restrict__ dst, int n8) {
    int gid = blockIdx.x * 256 + threadIdx.x;
    if (gid >= n8) return;
    const float4* s = (const float4*)src + (size_t)gid * 2;
    float4 a = s[0], b = s[1];
    short8 o;
    o[0] = (short)f2bf(a.x); o[1] = (short)f2bf(a.y); o[2] = (short)f2bf(a.z); o[3] = (short)f2bf(a.w);
    o[4] = (short)f2bf(b.x); o[5] = (short)f2bf(b.y); o[6] = (short)f2bf(b.z); o[7] = (short)f2bf(b.w);
    *((short8*)dst + gid) = o;
}

__global__ __launch_bounds__(256) void trig_kernel(float2* __restrict__ cs) {
    int id = blockIdx.x * 256 + threadIdx.x;   // < 2048*64
    int s = id >> 6, d = id & 63;
    float freq = expf(-(float)(2 * d) * (1.0f / (float)HD) * 9.210340371976184f); // ln(10000)
    float ang = (float)s * freq;
    cs[id] = make_float2(cosf(ang), sinf(ang));
}

__global__ __launch_bounds__(256) void ln_kernel(
    const float* __restrict__ X, const float* __restrict__ W, const float* __restrict__ Bv,
    u16* __restrict__ out) {
    const int row = blockIdx.x, tid = threadIdx.x;
    const float* xr = X + (size_t)row * HID;
    float4 v0 = ((const float4*)xr)[tid * 2];
    float4 v1 = ((const float4*)xr)[tid * 2 + 1];
    float e[8] = {v0.x, v0.y, v0.z, v0.w, v1.x, v1.y, v1.z, v1.w};
    float s = 0.f, ss2 = 0.f;
#pragma unroll
    for (int i = 0; i < 8; ++i) { s += e[i]; ss2 += e[i] * e[i]; }
#pragma unroll
    for (int m = 1; m < 64; m <<= 1) { s += __shfl_xor(s, m, 64); ss2 += __shfl_xor(ss2, m, 64); }
    __shared__ float red[8];
    if ((tid & 63) == 0) { red[tid >> 6] = s; red[4 + (tid >> 6)] = ss2; }
    __syncthreads();
    s = red[0] + red[1] + red[2] + red[3];
    ss2 = red[4] + red[5] + red[6] + red[7];
    float mean = s * (1.0f / HID);
    float var = ss2 * (1.0f / HID) - mean * mean;
    float rstd = rsqrtf(var + 1e-5f);
    float4 w0 = ((const float4*)W)[tid * 2], w1 = ((const float4*)W)[tid * 2 + 1];
    float4 b0 = ((const float4*)Bv)[tid * 2], b1 = ((const float4*)Bv)[tid * 2 + 1];
    float wv[8] = {w0.x, w0.y, w0.z, w0.w, w1.x, w1.y, w1.z, w1.w};
    float bv[8] = {b0.x, b0.y, b0.z, b0.w, b1.x, b1.y, b1.z, b1.w};
    short8 o;
#pragma unroll
    for (int i = 0; i < 8; ++i) o[i] = (short)f2bf((e[i] - mean) * rstd * wv[i] + bv[i]);
    *((short8*)(out + (size_t)row * HID) + tid) = o;
}

// RoPE on bf16 input (row stride 6144: reads q or k slice of fused qkv buffer)
__global__ __launch_bounds__(256) void rope_kernel(
    const u16* __restrict__ src, u16* __restrict__ dst, const float2* __restrict__ cs) {
    int gid = blockIdx.x * 256 + threadIdx.x;   // < 4096*16*64
    int d = gid & 63;
    int rh = gid >> 6;
    int h = rh & (NH - 1);
    int row = rh >> 4;               // b*2048+s
    int s = row & (SS - 1);
    unsigned pair = *(const unsigned*)(src + (size_t)row * 6144 + h * HD + 2 * d);
    float x1 = bf2f((u16)(pair & 0xFFFFu));
    float x2 = bf2f((u16)(pair >> 16));
    float2 t = cs[s * 64 + d];
    u16* q = dst + (size_t)row * HID + h * HD;
    q[d] = f2bf(x1 * t.x - x2 * t.y);
    q[64 + d] = f2bf(x1 * t.y + x2 * t.x);
}

// ---------------- GEMM: C[.,.] = A[M,K] * B[N,K]^T (bf16 in, fp32 acc) ----------------
// m97 structure: 128x128 tile, BK=32, 4 waves (each 64x64), global_load_lds width=16,
// staging-side pre-swizzle of the global source (rule #21: swizzle both sides or neither).

template <int OUT_BF16, int RESID>
__global__ __launch_bounds__(256) void gemm_bt(
    const u16* __restrict__ A, const u16* __restrict__ B,
    void* __restrict__ C, const float* __restrict__ resid,
    int ldc, int K) {
    __shared__ u16 As[128 * 32];
    __shared__ u16 Bs[128 * 32];
    const int tid = threadIdx.x;
    const int lane = tid & 63;
    const int wid = tid >> 6;
    const int lrow = lane & 15, lg = lane >> 4;
    const int m0 = blockIdx.y * 128, n0 = blockIdx.x * 128;
    const int wr = (wid >> 1) * 64, wn = (wid & 1) * 64;

    const int c0 = tid, c1 = tid + 256;
    const int r0 = c0 >> 2, k0c = ((c0 & 3) ^ ((c0 >> 3) & 3)) * 8;
    const int r1 = c1 >> 2, k1c = ((c1 & 3) ^ ((c1 >> 3) & 3)) * 8;
    const u16* Ag0 = A + (size_t)(m0 + r0) * K + k0c;
    const u16* Ag1 = A + (size_t)(m0 + r1) * K + k1c;
    const u16* Bg0 = B + (size_t)(n0 + r0) * K + k0c;
    const u16* Bg1 = B + (size_t)(n0 + r1) * K + k1c;
    u16* Al0 = &As[c0 * 8]; u16* Al1 = &As[c1 * 8];
    u16* Bl0 = &Bs[c0 * 8]; u16* Bl1 = &Bs[c1 * 8];

    f32x4 acc[4][4] = {};

    for (int kk = 0; kk < K; kk += 32) {
        __syncthreads();
        gll16(Ag0 + kk, Al0);
        gll16(Ag1 + kk, Al1);
        gll16(Bg0 + kk, Bl0);
        gll16(Bg1 + kk, Bl1);
        __syncthreads();
        short8 af[4], bfr[4];
#pragma unroll
        for (int m = 0; m < 4; ++m) {
            int row = wr + m * 16 + lrow;
            af[m] = *(const short8*)&As[row * 32 + (lg ^ ((row >> 1) & 3)) * 8];
        }
#pragma unroll
        for (int n = 0; n < 4; ++n) {
            int row = wn + n * 16 + lrow;
            bfr[n] = *(const short8*)&Bs[row * 32 + (lg ^ ((row >> 1) & 3)) * 8];
        }
#pragma unroll
        for (int m = 0; m < 4; ++m)
#pragma unroll
            for (int n = 0; n < 4; ++n)
                acc[m][n] = __builtin_amdgcn_mfma_f32_16x16x32_bf16(af[m], bfr[n], acc[m][n], 0, 0, 0);
    }

#pragma unroll
    for (int m = 0; m < 4; ++m)
#pragma unroll
        for (int n = 0; n < 4; ++n)
#pragma unroll
            for (int j = 0; j < 4; ++j) {
                int gm = m0 + wr + m * 16 + 4 * lg + j;
                int gn = n0 + wn + n * 16 + lrow;
                float v = acc[m][n][j];
                if (RESID) v += resid[(size_t)gm * ldc + gn];
                if (OUT_BF16) ((u16*)C)[(size_t)gm * ldc + gn] = f2bf(v);
                else ((float*)C)[(size_t)gm * ldc + gn] = v;
            }
}

// Fused gate/up GEMM + SiLU: each block computes gate tile (Bg) and up tile (Bu)
// for the same (m0,n0), writes silu(g)*u as bf16.
__global__ __launch_bounds__(256) void gemm_gu(
    const u16* __restrict__ A, const u16* __restrict__ Bg, const u16* __restrict__ Bu,
    u16* __restrict__ C, int ldc, int K) {
    __shared__ u16 As[128 * 32];
    __shared__ u16 Gs[128 * 32];
    __shared__ u16 Us[128 * 32];
    const int tid = threadIdx.x;
    const int lane = tid & 63;
    const int wid = tid >> 6;
    const int lrow = lane & 15, lg = lane >> 4;
    const int m0 = blockIdx.y * 128, n0 = blockIdx.x * 128;
    const int wr = (wid >> 1) * 64, wn = (wid & 1) * 64;

    const int c0 = tid, c1 = tid + 256;
    const int r0 = c0 >> 2, k0c = ((c0 & 3) ^ ((c0 >> 3) & 3)) * 8;
    const int r1 = c1 >> 2, k1c = ((c1 & 3) ^ ((c1 >> 3) & 3)) * 8;
    const u16* Ag0 = A + (size_t)(m0 + r0) * K + k0c;
    const u16* Ag1 = A + (size_t)(m0 + r1) * K + k1c;
    const u16* Gg0 = Bg + (size_t)(n0 + r0) * K + k0c;
    const u16* Gg1 = Bg + (size_t)(n0 + r1) * K + k1c;
    const u16* Ug0 = Bu + (size_t)(n0 + r0) * K + k0c;
    const u16* Ug1 = Bu + (size_t)(n0 + r1) * K + k1c;
    u16* Al0 = &As[c0 * 8]; u16* Al1 = &As[c1 * 8];
    u16* Gl0 = &Gs[c0 * 8]; u16* Gl1 = &Gs[c1 * 8];
    u16* Ul0 = &Us[c0 * 8]; u16* Ul1 = &Us[c1 * 8];

    f32x4 accg[4][4] = {};
    f32x4 accu[4][4] = {};

    for (int kk = 0; kk < K; kk += 32) {
        __syncthreads();
        gll16(Ag0 + kk, Al0);
        gll16(Ag1 + kk, Al1);
        gll16(Gg0 + kk, Gl0);
        gll16(Gg1 + kk, Gl1);
        gll16(Ug0 + kk, Ul0);
        gll16(Ug1 + kk, Ul1);
        __syncthreads();
        short8 af[4], gf[4], uf[4];
#pragma unroll
        for (int m = 0; m < 4; ++m) {
            int row = wr + m * 16 + lrow;
            af[m] = *(const short8*)&As[row * 32 + (lg ^ ((row >> 1) & 3)) * 8];
        }
#pragma unroll
        for (int n = 0; n < 4; ++n) {
            int row = wn + n * 16 + lrow;
            gf[n] = *(const short8*)&Gs[row * 32 + (lg ^ ((row >> 1) & 3)) * 8];
            uf[n] = *(const short8*)&Us[row * 32 + (lg ^ ((row >> 1) & 3)) * 8];
        }
#pragma unroll
        for (int m = 0; m < 4; ++m)
#pragma unroll
            for (int n = 0; n < 4; ++n) {
                accg[m][n] = __builtin_amdgcn_mfma_f32_16x16x32_bf16(af[m], gf[n], accg[m][n], 0, 0, 0);
                accu[m][n] = __builtin_amdgcn_mfma_f32_16x16x32_bf16(af[m], uf[n], accu[m][n], 0, 0, 0);
            }
    }

#pragma unroll
    for (int m = 0; m < 4; ++m)
#pragma unroll
        for (int n = 0; n < 4; ++n)
#pragma unroll
            for (int j = 0; j < 4; ++j) {
                int gm = m0 + wr + m * 16 + 4 * lg + j;
                int gn = n0 + wn + n * 16 + lrow;
                float g = accg[m][n][j];
                float u = accu[m][n][j];
                float v = g / (1.f + __expf(-g)) * u;
                C[(size_t)gm * ldc + gn] = f2bf(v);
            }
}

// ---------------- flash attention (causal), 64-row Q tiles, 4 waves ----------------

__global__ __launch_bounds__(256) void attn_kernel(
    const u16* __restrict__ Q, const u16* __restrict__ K, const u16* __restrict__ V,
    u16* __restrict__ O, int vstride) {
    const int bh = blockIdx.y;
    const int b = bh >> 4, h = bh & 15;
    const int q0 = blockIdx.x * 64;
    const int tid = threadIdx.x, wid = tid >> 6, lane = tid & 63;
    const int lrow = lane & 15, lg = lane >> 4;

    __shared__ u16 Ks[64 * 128];     // swizzled: byte = r*256 + 2*d ^ ((r&7)<<4)
    __shared__ u16 Vt[128 * 64];     // transposed: byte = d*128 + 2*k ^ ((d&7)<<4)
    __shared__ u16 Ps[4][16 * 64];   // per-wave P: byte = row*128 + 2*col ^ ((row&7)<<4)

    const int qrow = q0 + wid * 16;
    short8 qf[4];
    {
        const u16* Qb = Q + ((size_t)(b * SS + qrow + lrow)) * HID + h * HD;
#pragma unroll
        for (int kc = 0; kc < 4; ++kc) qf[kc] = *(const short8*)(Qb + kc * 32 + lg * 8);
    }

    f32x4 oacc[8] = {};
    float mrun[4] = {-3e38f, -3e38f, -3e38f, -3e38f};
    float lrun[4] = {0.f, 0.f, 0.f, 0.f};
    const float scale = 0.08838834764831845f;   // 1/sqrt(128)

    for (int j0 = 0; j0 <= q0; j0 += 64) {
        __syncthreads();
        for (int c = tid; c < 1024; c += 256) {       // K tile: coalesced rows
            int r = c >> 4, dc = (c & 15) * 8;
            short8 kv = *(const short8*)(K + ((size_t)(b * SS + j0 + r)) * HID + h * HD + dc);
            *(short8*)((char*)Ks + ((r * 256 + dc * 2) ^ ((r & 7) << 4))) = kv;
        }
        for (int c = tid; c < 1024; c += 256) {       // V tile: transpose into Vt
            int r = c & 63, dc = (c >> 6) * 8;
            short8 vv = *(const short8*)(V + ((size_t)(b * SS + j0 + r)) * vstride + h * HD + dc);
#pragma unroll
            for (int i = 0; i < 8; ++i) {
                int d = dc + i;
                *(u16*)((char*)Vt + ((d * 128 + 2 * r) ^ ((d & 7) << 4))) = (u16)vv[i];
            }
        }
        __syncthreads();

        f32x4 sacc[4] = {};
#pragma unroll
        for (int n = 0; n < 4; ++n) {
#pragma unroll
            for (int kc = 0; kc < 4; ++kc) {
                int r = n * 16 + lrow;
                short8 kf = *(const short8*)((const char*)Ks +
                            ((r * 256 + (kc * 32 + lg * 8) * 2) ^ ((r & 7) << 4)));
                sacc[n] = __builtin_amdgcn_mfma_f32_16x16x32_bf16(qf[kc], kf, sacc[n], 0, 0, 0);
            }
        }

        const bool diag = (j0 == q0);
        float pm[4] = {-3e38f, -3e38f, -3e38f, -3e38f};
#pragma unroll
        for (int n = 0; n < 4; ++n)
#pragma unroll
            for (int j = 0; j < 4; ++j) {
                float sv = sacc[n][j] * scale;
                if (diag && (n * 16 + lrow > wid * 16 + 4 * lg + j)) sv = -1e30f;
                sacc[n][j] = sv;
                pm[j] = fmaxf(pm[j], sv);
            }
#pragma unroll
        for (int j = 0; j < 4; ++j)
#pragma unroll
            for (int m = 1; m < 16; m <<= 1) pm[j] = fmaxf(pm[j], __shfl_xor(pm[j], m, 64));

        float sf[4], rs[4];
#pragma unroll
        for (int j = 0; j < 4; ++j) {
            float mnew = fmaxf(mrun[j], pm[j]);
            sf[j] = __expf(mrun[j] - mnew);
            mrun[j] = mnew;
            rs[j] = 0.f;
        }
#pragma unroll
        for (int n = 0; n < 4; ++n)
#pragma unroll
            for (int j = 0; j < 4; ++j) {
                float p = __expf(sacc[n][j] - mrun[j]);
                sacc[n][j] = p;
                rs[j] += p;
            }
#pragma unroll
        for (int j = 0; j < 4; ++j) {
#pragma unroll
            for (int m = 1; m < 16; m <<= 1) rs[j] += __shfl_xor(rs[j], m, 64);
            lrun[j] = lrun[j] * sf[j] + rs[j];
        }
#pragma unroll
        for (int n = 0; n < 8; ++n)
#pragma unroll
            for (int j = 0; j < 4; ++j) oacc[n][j] *= sf[j];

#pragma unroll
        for (int n = 0; n < 4; ++n)
#pragma unroll
            for (int j = 0; j < 4; ++j) {
                int row = 4 * lg + j, col = n * 16 + lrow;
                *(u16*)((char*)&Ps[wid][0] + ((row * 128 + col * 2) ^ ((row & 7) << 4))) =
                    f2bf(sacc[n][j]);
            }
        __syncthreads();
        short8 pf[2];
#pragma unroll
        for (int ks = 0; ks < 2; ++ks)
            pf[ks] = *(const short8*)((const char*)&Ps[wid][0] +
                     ((lrow * 128 + (ks * 32 + lg * 8) * 2) ^ ((lrow & 7) << 4)));
#pragma unroll
        for (int n = 0; n < 8; ++n) {
            int d = n * 16 + lrow;
#pragma unroll
            for (int ks = 0; ks < 2; ++ks) {
                short8 vf = *(const short8*)((const char*)Vt +
                            ((d * 128 + (ks * 32 + lg * 8) * 2) ^ ((d & 7) << 4)));
                oacc[n] = __builtin_amdgcn_mfma_f32_16x16x32_bf16(pf[ks], vf, oacc[n], 0, 0, 0);
            }
        }
    }

#pragma unroll
    for (int n = 0; n < 8; ++n)
#pragma unroll
        for (int j = 0; j < 4; ++j) {
            int row = qrow + 4 * lg + j;
            O[((size_t)(b * SS + row)) * HID + h * HD + n * 16 + lrow] =
                f2bf(oacc[n][j] / lrun[j]);
        }
}

// ---------------- launcher ----------------

extern "C" void kernel_launch(void* const* d_in, const int* in_sizes, int n_in,
                              void* d_out, int out_size, void* d_ws, size_t ws_size,
                              hipStream_t stream) {
    const float* x    = (const float*)d_in[0];
    const float* ln1w = (const float*)d_in[1];
    const float* ln1b = (const float*)d_in[2];
    const float* ln2w = (const float*)d_in[3];
    const float* ln2b = (const float*)d_in[4];
    const float* wq   = (const float*)d_in[5];
    const float* wk   = (const float*)d_in[6];
    const float* wv   = (const float*)d_in[7];
    const float* wo   = (const float*)d_in[8];
    const float* wg   = (const float*)d_in[9];
    const float* wu   = (const float*)d_in[10];
    const float* wd   = (const float*)d_in[11];

    char* ws = (char*)d_ws;
    // 177 MiB total footprint:
    u16*    Wbuf = (u16*)(ws);                       // 32 MiB, reused per-GEMM
    u16*    hb   = (u16*)(ws + (32UL << 20));        // 16 MiB  LN out (bf16)
    u16*    qkvb = (u16*)(ws + (48UL << 20));        // 48 MiB  QKV bf16 [4096][6144]
    u16*    qb   = (u16*)(ws + (96UL << 20));        // 16 MiB
    u16*    kb   = (u16*)(ws + (112UL << 20));       // 16 MiB
    u16*    ob   = (u16*)(ws + (128UL << 20));       // 16 MiB
    float*  x2   = (float*)(ws + (144UL << 20));     // 32 MiB  fp32 residual stream
    float2* cs   = (float2*)(ws + (176UL << 20));    // 1 MiB   rope cos/sin
    u16*    mb   = qkvb;                             // 64 MiB alias (qkvb+qb, both dead by MLP)

    trig_kernel<<<512, 256, 0, stream>>>(cs);
    ln_kernel<<<4096, 256, 0, stream>>>(x, ln1w, ln1b, hb);

    // QKV projection (weights cast just-in-time into Wbuf: [wq;wk;wv] = 24 MiB)
    cast_f32_bf16_kernel<<<2048, 256, 0, stream>>>(wq, Wbuf, 524288);
    cast_f32_bf16_kernel<<<2048, 256, 0, stream>>>(wk, Wbuf + 4194304, 524288);
    cast_f32_bf16_kernel<<<2048, 256, 0, stream>>>(wv, Wbuf + 8388608, 524288);
    gemm_bt<1, 0><<<dim3(48, 32), 256, 0, stream>>>(hb, Wbuf, qkvb, nullptr, 6144, 2048);

    rope_kernel<<<16384, 256, 0, stream>>>(qkvb, qb, cs);
    rope_kernel<<<16384, 256, 0, stream>>>(qkvb + 2048, kb, cs);
    attn_kernel<<<dim3(32, 32), 256, 0, stream>>>(qb, kb, qkvb + 4096, ob, 6144);

    // O projection + residual (fp32 out)
    cast_f32_bf16_kernel<<<2048, 256, 0, stream>>>(wo, Wbuf, 524288);
    gemm_bt<0, 1><<<dim3(16, 32), 256, 0, stream>>>(ob, Wbuf, x2, x, 2048, 2048);

    ln_kernel<<<4096, 256, 0, stream>>>(x2, ln2w, ln2b, hb);

    // MLP gate/up in two 4096-column halves (SiLU fused in epilogue)
    for (int h = 0; h < 2; ++h) {
        cast_f32_bf16_kernel<<<4096, 256, 0, stream>>>(wg + (size_t)h * 8388608, Wbuf, 1048576);
        cast_f32_bf16_kernel<<<4096, 256, 0, stream>>>(wu + (size_t)h * 8388608, Wbuf + 8388608, 1048576);
        gemm_gu<<<dim3(32, 32), 256, 0, stream>>>(hb, Wbuf, Wbuf + 8388608,
                                                  mb + h * 4096, 8192, 2048);
    }

    // Down projection + residual -> fp32 d_out
    cast_f32_bf16_kernel<<<8192, 256, 0, stream>>>(wd, Wbuf, 2097152);
    gemm_bt<0, 1><<<dim3(16, 32), 256, 0, stream>>>(mb, Wbuf, (float*)d_out, x2, 2048, 8192);
}

// Round 3
// 1155.347 us; speedup vs baseline: 1.1802x; 1.1802x over previous
//
#include <hip/hip_runtime.h>
#include <hip/hip_bf16.h>

#define HID 2048
#define NH 16
#define HD 128
#define INTER 8192
#define SS 2048

typedef unsigned short u16;
typedef __attribute__((ext_vector_type(8))) short short8;
typedef __attribute__((ext_vector_type(4))) float f32x4;

__device__ __forceinline__ float bf2f(u16 u) {
    unsigned v = ((unsigned)u) << 16; float f; __builtin_memcpy(&f, &v, 4); return f;
}
__device__ __forceinline__ u16 f2bf(float f) {
    unsigned u; __builtin_memcpy(&u, &f, 4);
    u = u + 0x7FFFu + ((u >> 16) & 1u);   // RNE
    return (u16)(u >> 16);
}

typedef const __attribute__((address_space(1))) void* gas_t;
typedef __attribute__((address_space(3))) void* las_t;
__device__ __forceinline__ void gll16(const void* g, void* l) {
    __builtin_amdgcn_global_load_lds((gas_t)g, (las_t)l, 16, 0, 0);
}

// ---------------- elementwise / prep kernels ----------------

__global__ __launch_bounds__(256) void cast_f32_bf16_kernel(
    const float* __restrict__ src, u16* __restrict__ dst, int n8) {
    int gid = blockIdx.x * 256 + threadIdx.x;
    if (gid >= n8) return;
    const float4* s = (const float4*)src + (size_t)gid * 2;
    float4 a = s[0], b = s[1];
    short8 o;
    o[0] = (short)f2bf(a.x); o[1] = (short)f2bf(a.y); o[2] = (short)f2bf(a.z); o[3] = (short)f2bf(a.w);
    o[4] = (short)f2bf(b.x); o[5] = (short)f2bf(b.y); o[6] = (short)f2bf(b.z); o[7] = (short)f2bf(b.w);
    *((short8*)dst + gid) = o;
}

__global__ __launch_bounds__(256) void trig_kernel(float2* __restrict__ cs) {
    int id = blockIdx.x * 256 + threadIdx.x;   // < 2048*64
    int s = id >> 6, d = id & 63;
    float freq = expf(-(float)(2 * d) * (1.0f / (float)HD) * 9.210340371976184f); // ln(10000)
    float ang = (float)s * freq;
    cs[id] = make_float2(cosf(ang), sinf(ang));
}

__global__ __launch_bounds__(256) void ln_kernel(
    const float* __restrict__ X, const float* __restrict__ W, const float* __restrict__ Bv,
    u16* __restrict__ out) {
    const int row = blockIdx.x, tid = threadIdx.x;
    const float* xr = X + (size_t)row * HID;
    float4 v0 = ((const float4*)xr)[tid * 2];
    float4 v1 = ((const float4*)xr)[tid * 2 + 1];
    float e[8] = {v0.x, v0.y, v0.z, v0.w, v1.x, v1.y, v1.z, v1.w};
    float s = 0.f, ss2 = 0.f;
#pragma unroll
    for (int i = 0; i < 8; ++i) { s += e[i]; ss2 += e[i] * e[i]; }
#pragma unroll
    for (int m = 1; m < 64; m <<= 1) { s += __shfl_xor(s, m, 64); ss2 += __shfl_xor(ss2, m, 64); }
    __shared__ float red[8];
    if ((tid & 63) == 0) { red[tid >> 6] = s; red[4 + (tid >> 6)] = ss2; }
    __syncthreads();
    s = red[0] + red[1] + red[2] + red[3];
    ss2 = red[4] + red[5] + red[6] + red[7];
    float mean = s * (1.0f / HID);
    float var = ss2 * (1.0f / HID) - mean * mean;
    float rstd = rsqrtf(var + 1e-5f);
    float4 w0 = ((const float4*)W)[tid * 2], w1 = ((const float4*)W)[tid * 2 + 1];
    float4 b0 = ((const float4*)Bv)[tid * 2], b1 = ((const float4*)Bv)[tid * 2 + 1];
    float wv[8] = {w0.x, w0.y, w0.z, w0.w, w1.x, w1.y, w1.z, w1.w};
    float bv[8] = {b0.x, b0.y, b0.z, b0.w, b1.x, b1.y, b1.z, b1.w};
    short8 o;
#pragma unroll
    for (int i = 0; i < 8; ++i) o[i] = (short)f2bf((e[i] - mean) * rstd * wv[i] + bv[i]);
    *((short8*)(out + (size_t)row * HID) + tid) = o;
}

// RoPE on bf16 input (row stride 6144: reads q or k slice of fused qkv buffer)
__global__ __launch_bounds__(256) void rope_kernel(
    const u16* __restrict__ src, u16* __restrict__ dst, const float2* __restrict__ cs) {
    int gid = blockIdx.x * 256 + threadIdx.x;   // < 4096*16*64
    int d = gid & 63;
    int rh = gid >> 6;
    int h = rh & (NH - 1);
    int row = rh >> 4;               // b*2048+s
    int s = row & (SS - 1);
    unsigned pair = *(const unsigned*)(src + (size_t)row * 6144 + h * HD + 2 * d);
    float x1 = bf2f((u16)(pair & 0xFFFFu));
    float x2 = bf2f((u16)(pair >> 16));
    float2 t = cs[s * 64 + d];
    u16* q = dst + (size_t)row * HID + h * HD;
    q[d] = f2bf(x1 * t.x - x2 * t.y);
    q[64 + d] = f2bf(x1 * t.y + x2 * t.x);
}

// ---------------- GEMM: C[.,.] = A[M,K] * B[N,K]^T (bf16 in, fp32 acc) ----------------
// m97 structure: 128x128 tile, BK=32, 4 waves (each 64x64), global_load_lds width=16,
// staging-side pre-swizzle of the global source (rule #21: swizzle both sides or neither).

template <int OUT_BF16, int RESID>
__global__ __launch_bounds__(256) void gemm_bt(
    const u16* __restrict__ A, const u16* __restrict__ B,
    void* __restrict__ C, const float* __restrict__ resid,
    int ldc, int K) {
    __shared__ u16 As[128 * 32];
    __shared__ u16 Bs[128 * 32];
    const int tid = threadIdx.x;
    const int lane = tid & 63;
    const int wid = tid >> 6;
    const int lrow = lane & 15, lg = lane >> 4;
    const int m0 = blockIdx.y * 128, n0 = blockIdx.x * 128;
    const int wr = (wid >> 1) * 64, wn = (wid & 1) * 64;

    const int c0 = tid, c1 = tid + 256;
    const int r0 = c0 >> 2, k0c = ((c0 & 3) ^ ((c0 >> 3) & 3)) * 8;
    const int r1 = c1 >> 2, k1c = ((c1 & 3) ^ ((c1 >> 3) & 3)) * 8;
    const u16* Ag0 = A + (size_t)(m0 + r0) * K + k0c;
    const u16* Ag1 = A + (size_t)(m0 + r1) * K + k1c;
    const u16* Bg0 = B + (size_t)(n0 + r0) * K + k0c;
    const u16* Bg1 = B + (size_t)(n0 + r1) * K + k1c;
    u16* Al0 = &As[c0 * 8]; u16* Al1 = &As[c1 * 8];
    u16* Bl0 = &Bs[c0 * 8]; u16* Bl1 = &Bs[c1 * 8];

    f32x4 acc[4][4] = {};

    for (int kk = 0; kk < K; kk += 32) {
        __syncthreads();
        gll16(Ag0 + kk, Al0);
        gll16(Ag1 + kk, Al1);
        gll16(Bg0 + kk, Bl0);
        gll16(Bg1 + kk, Bl1);
        __syncthreads();
        short8 af[4], bfr[4];
#pragma unroll
        for (int m = 0; m < 4; ++m) {
            int row = wr + m * 16 + lrow;
            af[m] = *(const short8*)&As[row * 32 + (lg ^ ((row >> 1) & 3)) * 8];
        }
#pragma unroll
        for (int n = 0; n < 4; ++n) {
            int row = wn + n * 16 + lrow;
            bfr[n] = *(const short8*)&Bs[row * 32 + (lg ^ ((row >> 1) & 3)) * 8];
        }
#pragma unroll
        for (int m = 0; m < 4; ++m)
#pragma unroll
            for (int n = 0; n < 4; ++n)
                acc[m][n] = __builtin_amdgcn_mfma_f32_16x16x32_bf16(af[m], bfr[n], acc[m][n], 0, 0, 0);
    }

#pragma unroll
    for (int m = 0; m < 4; ++m)
#pragma unroll
        for (int n = 0; n < 4; ++n)
#pragma unroll
            for (int j = 0; j < 4; ++j) {
                int gm = m0 + wr + m * 16 + 4 * lg + j;
                int gn = n0 + wn + n * 16 + lrow;
                float v = acc[m][n][j];
                if (RESID) v += resid[(size_t)gm * ldc + gn];
                if (OUT_BF16) ((u16*)C)[(size_t)gm * ldc + gn] = f2bf(v);
                else ((float*)C)[(size_t)gm * ldc + gn] = v;
            }
}

// Fused gate/up GEMM + SiLU. 128x64-per-matrix tile (grid N/64 x M/128): block
// computes gate tile and up tile for the same (m0,n0), writes silu(g)*u as bf16.
// Per-wave acc = 4x2 per matrix = 16 f32x4 total -> same register budget as
// gemm_bt (the previous 4x4x2 = 32 f32x4 variant was reg-limited to 1 wave/SIMD,
// OccupancyPercent 11.7 -> this one targets ~25).
__global__ __launch_bounds__(256) void gemm_gu(
    const u16* __restrict__ A, const u16* __restrict__ Bg, const u16* __restrict__ Bu,
    u16* __restrict__ C, int ldc, int K) {
    __shared__ u16 As[128 * 32];
    __shared__ u16 Gs[64 * 32];
    __shared__ u16 Us[64 * 32];
    const int tid = threadIdx.x;
    const int lane = tid & 63;
    const int wid = tid >> 6;
    const int lrow = lane & 15, lg = lane >> 4;
    const int m0 = blockIdx.y * 128, n0 = blockIdx.x * 64;
    const int wr = (wid >> 1) * 64, wn = (wid & 1) * 32;

    const int c0 = tid, c1 = tid + 256;
    const int ra0 = c0 >> 2, ka0 = ((c0 & 3) ^ ((c0 >> 3) & 3)) * 8;
    const int ra1 = c1 >> 2, ka1 = ((c1 & 3) ^ ((c1 >> 3) & 3)) * 8;
    const int rg = tid >> 2, kg = ((tid & 3) ^ ((tid >> 3) & 3)) * 8;
    const u16* Ag0 = A + (size_t)(m0 + ra0) * K + ka0;
    const u16* Ag1 = A + (size_t)(m0 + ra1) * K + ka1;
    const u16* Gg = Bg + (size_t)(n0 + rg) * K + kg;
    const u16* Ug = Bu + (size_t)(n0 + rg) * K + kg;
    u16* Al0 = &As[c0 * 8]; u16* Al1 = &As[c1 * 8];
    u16* Gl = &Gs[tid * 8]; u16* Ul = &Us[tid * 8];

    f32x4 accg[4][2] = {};
    f32x4 accu[4][2] = {};

    for (int kk = 0; kk < K; kk += 32) {
        __syncthreads();
        gll16(Ag0 + kk, Al0);
        gll16(Ag1 + kk, Al1);
        gll16(Gg + kk, Gl);
        gll16(Ug + kk, Ul);
        __syncthreads();
        short8 af[4], gf[2], uf[2];
#pragma unroll
        for (int m = 0; m < 4; ++m) {
            int row = wr + m * 16 + lrow;
            af[m] = *(const short8*)&As[row * 32 + (lg ^ ((row >> 1) & 3)) * 8];
        }
#pragma unroll
        for (int n = 0; n < 2; ++n) {
            int row = wn + n * 16 + lrow;
            gf[n] = *(const short8*)&Gs[row * 32 + (lg ^ ((row >> 1) & 3)) * 8];
            uf[n] = *(const short8*)&Us[row * 32 + (lg ^ ((row >> 1) & 3)) * 8];
        }
#pragma unroll
        for (int m = 0; m < 4; ++m)
#pragma unroll
            for (int n = 0; n < 2; ++n) {
                accg[m][n] = __builtin_amdgcn_mfma_f32_16x16x32_bf16(af[m], gf[n], accg[m][n], 0, 0, 0);
                accu[m][n] = __builtin_amdgcn_mfma_f32_16x16x32_bf16(af[m], uf[n], accu[m][n], 0, 0, 0);
            }
    }

#pragma unroll
    for (int m = 0; m < 4; ++m)
#pragma unroll
        for (int n = 0; n < 2; ++n)
#pragma unroll
            for (int j = 0; j < 4; ++j) {
                int gm = m0 + wr + m * 16 + 4 * lg + j;
                int gn = n0 + wn + n * 16 + lrow;
                float g = accg[m][n][j];
                float u = accu[m][n][j];
                float v = g / (1.f + __expf(-g)) * u;
                C[(size_t)gm * ldc + gn] = f2bf(v);
            }
}

// ---------------- flash attention (causal), 64-row Q tiles, 4 waves ----------------

__global__ __launch_bounds__(256) void attn_kernel(
    const u16* __restrict__ Q, const u16* __restrict__ K, const u16* __restrict__ V,
    u16* __restrict__ O, int vstride) {
    const int bh = blockIdx.y;
    const int b = bh >> 4, h = bh & 15;
    const int q0 = blockIdx.x * 64;
    const int tid = threadIdx.x, wid = tid >> 6, lane = tid & 63;
    const int lrow = lane & 15, lg = lane >> 4;

    __shared__ u16 Ks[64 * 128];     // swizzled: byte = r*256 + 2*d ^ ((r&7)<<4)
    __shared__ u16 Vt[128 * 64];     // transposed: byte = d*128 + 2*k ^ ((d&7)<<4)
    __shared__ u16 Ps[4][16 * 64];   // per-wave P: byte = row*128 + 2*col ^ ((row&7)<<4)

    const int qrow = q0 + wid * 16;
    short8 qf[4];
    {
        const u16* Qb = Q + ((size_t)(b * SS + qrow + lrow)) * HID + h * HD;
#pragma unroll
        for (int kc = 0; kc < 4; ++kc) qf[kc] = *(const short8*)(Qb + kc * 32 + lg * 8);
    }

    f32x4 oacc[8] = {};
    float mrun[4] = {-3e38f, -3e38f, -3e38f, -3e38f};
    float lrun[4] = {0.f, 0.f, 0.f, 0.f};
    const float scale = 0.08838834764831845f;   // 1/sqrt(128)

    for (int j0 = 0; j0 <= q0; j0 += 64) {
        __syncthreads();
        for (int c = tid; c < 1024; c += 256) {       // K tile: coalesced rows
            int r = c >> 4, dc = (c & 15) * 8;
            short8 kv = *(const short8*)(K + ((size_t)(b * SS + j0 + r)) * HID + h * HD + dc);
            *(short8*)((char*)Ks + ((r * 256 + dc * 2) ^ ((r & 7) << 4))) = kv;
        }
        for (int c = tid; c < 1024; c += 256) {       // V tile: transpose into Vt
            int r = c & 63, dc = (c >> 6) * 8;
            short8 vv = *(const short8*)(V + ((size_t)(b * SS + j0 + r)) * vstride + h * HD + dc);
#pragma unroll
            for (int i = 0; i < 8; ++i) {
                int d = dc + i;
                *(u16*)((char*)Vt + ((d * 128 + 2 * r) ^ ((d & 7) << 4))) = (u16)vv[i];
            }
        }
        __syncthreads();

        f32x4 sacc[4] = {};
#pragma unroll
        for (int n = 0; n < 4; ++n) {
#pragma unroll
            for (int kc = 0; kc < 4; ++kc) {
                int r = n * 16 + lrow;
                short8 kf = *(const short8*)((const char*)Ks +
                            ((r * 256 + (kc * 32 + lg * 8) * 2) ^ ((r & 7) << 4)));
                sacc[n] = __builtin_amdgcn_mfma_f32_16x16x32_bf16(qf[kc], kf, sacc[n], 0, 0, 0);
            }
        }

        const bool diag = (j0 == q0);
        float pm[4] = {-3e38f, -3e38f, -3e38f, -3e38f};
#pragma unroll
        for (int n = 0; n < 4; ++n)
#pragma unroll
            for (int j = 0; j < 4; ++j) {
                float sv = sacc[n][j] * scale;
                if (diag && (n * 16 + lrow > wid * 16 + 4 * lg + j)) sv = -1e30f;
                sacc[n][j] = sv;
                pm[j] = fmaxf(pm[j], sv);
            }
#pragma unroll
        for (int j = 0; j < 4; ++j)
#pragma unroll
            for (int m = 1; m < 16; m <<= 1) pm[j] = fmaxf(pm[j], __shfl_xor(pm[j], m, 64));

        float sf[4], rs[4];
#pragma unroll
        for (int j = 0; j < 4; ++j) {
            float mnew = fmaxf(mrun[j], pm[j]);
            sf[j] = __expf(mrun[j] - mnew);
            mrun[j] = mnew;
            rs[j] = 0.f;
        }
#pragma unroll
        for (int n = 0; n < 4; ++n)
#pragma unroll
            for (int j = 0; j < 4; ++j) {
                float p = __expf(sacc[n][j] - mrun[j]);
                sacc[n][j] = p;
                rs[j] += p;
            }
#pragma unroll
        for (int j = 0; j < 4; ++j) {
#pragma unroll
            for (int m = 1; m < 16; m <<= 1) rs[j] += __shfl_xor(rs[j], m, 64);
            lrun[j] = lrun[j] * sf[j] + rs[j];
        }
#pragma unroll
        for (int n = 0; n < 8; ++n)
#pragma unroll
            for (int j = 0; j < 4; ++j) oacc[n][j] *= sf[j];

#pragma unroll
        for (int n = 0; n < 4; ++n)
#pragma unroll
            for (int j = 0; j < 4; ++j) {
                int row = 4 * lg + j, col = n * 16 + lrow;
                *(u16*)((char*)&Ps[wid][0] + ((row * 128 + col * 2) ^ ((row & 7) << 4))) =
                    f2bf(sacc[n][j]);
            }
        __syncthreads();
        short8 pf[2];
#pragma unroll
        for (int ks = 0; ks < 2; ++ks)
            pf[ks] = *(const short8*)((const char*)&Ps[wid][0] +
                     ((lrow * 128 + (ks * 32 + lg * 8) * 2) ^ ((lrow & 7) << 4)));
#pragma unroll
        for (int n = 0; n < 8; ++n) {
            int d = n * 16 + lrow;
#pragma unroll
            for (int ks = 0; ks < 2; ++ks) {
                short8 vf = *(const short8*)((const char*)Vt +
                            ((d * 128 + (ks * 32 + lg * 8) * 2) ^ ((d & 7) << 4)));
                oacc[n] = __builtin_amdgcn_mfma_f32_16x16x32_bf16(pf[ks], vf, oacc[n], 0, 0, 0);
            }
        }
    }

#pragma unroll
    for (int n = 0; n < 8; ++n)
#pragma unroll
        for (int j = 0; j < 4; ++j) {
            int row = qrow + 4 * lg + j;
            O[((size_t)(b * SS + row)) * HID + h * HD + n * 16 + lrow] =
                f2bf(oacc[n][j] / lrun[j]);
        }
}

// ---------------- launcher ----------------

extern "C" void kernel_launch(void* const* d_in, const int* in_sizes, int n_in,
                              void* d_out, int out_size, void* d_ws, size_t ws_size,
                              hipStream_t stream) {
    const float* x    = (const float*)d_in[0];
    const float* ln1w = (const float*)d_in[1];
    const float* ln1b = (const float*)d_in[2];
    const float* ln2w = (const float*)d_in[3];
    const float* ln2b = (const float*)d_in[4];
    const float* wq   = (const float*)d_in[5];
    const float* wk   = (const float*)d_in[6];
    const float* wv   = (const float*)d_in[7];
    const float* wo   = (const float*)d_in[8];
    const float* wg   = (const float*)d_in[9];
    const float* wu   = (const float*)d_in[10];
    const float* wd   = (const float*)d_in[11];

    char* ws = (char*)d_ws;
    // 177 MiB total footprint:
    u16*    Wbuf = (u16*)(ws);                       // 32 MiB, reused per-GEMM
    u16*    hb   = (u16*)(ws + (32UL << 20));        // 16 MiB  LN out (bf16)
    u16*    qkvb = (u16*)(ws + (48UL << 20));        // 48 MiB  QKV bf16 [4096][6144]
    u16*    qb   = (u16*)(ws + (96UL << 20));        // 16 MiB
    u16*    kb   = (u16*)(ws + (112UL << 20));       // 16 MiB
    u16*    ob   = (u16*)(ws + (128UL << 20));       // 16 MiB
    float*  x2   = (float*)(ws + (144UL << 20));     // 32 MiB  fp32 residual stream
    float2* cs   = (float2*)(ws + (176UL << 20));    // 1 MiB   rope cos/sin
    u16*    mb   = qkvb;                             // 64 MiB alias (qkvb+qb, both dead by MLP)

    trig_kernel<<<512, 256, 0, stream>>>(cs);
    ln_kernel<<<4096, 256, 0, stream>>>(x, ln1w, ln1b, hb);

    // QKV projection (weights cast just-in-time into Wbuf: [wq;wk;wv] = 24 MiB)
    cast_f32_bf16_kernel<<<2048, 256, 0, stream>>>(wq, Wbuf, 524288);
    cast_f32_bf16_kernel<<<2048, 256, 0, stream>>>(wk, Wbuf + 4194304, 524288);
    cast_f32_bf16_kernel<<<2048, 256, 0, stream>>>(wv, Wbuf + 8388608, 524288);
    gemm_bt<1, 0><<<dim3(48, 32), 256, 0, stream>>>(hb, Wbuf, qkvb, nullptr, 6144, 2048);

    rope_kernel<<<16384, 256, 0, stream>>>(qkvb, qb, cs);
    rope_kernel<<<16384, 256, 0, stream>>>(qkvb + 2048, kb, cs);
    attn_kernel<<<dim3(32, 32), 256, 0, stream>>>(qb, kb, qkvb + 4096, ob, 6144);

    // O projection + residual (fp32 out)
    cast_f32_bf16_kernel<<<2048, 256, 0, stream>>>(wo, Wbuf, 524288);
    gemm_bt<0, 1><<<dim3(16, 32), 256, 0, stream>>>(ob, Wbuf, x2, x, 2048, 2048);

    ln_kernel<<<4096, 256, 0, stream>>>(x2, ln2w, ln2b, hb);

    // MLP gate/up in two 4096-column halves (SiLU fused in epilogue)
    for (int h = 0; h < 2; ++h) {
        cast_f32_bf16_kernel<<<4096, 256, 0, stream>>>(wg + (size_t)h * 8388608, Wbuf, 1048576);
        cast_f32_bf16_kernel<<<4096, 256, 0, stream>>>(wu + (size_t)h * 8388608, Wbuf + 8388608, 1048576);
        gemm_gu<<<dim3(64, 32), 256, 0, stream>>>(hb, Wbuf, Wbuf + 8388608,
                                                  mb + h * 4096, 8192, 2048);
    }

    // Down projection + residual -> fp32 d_out
    cast_f32_bf16_kernel<<<8192, 256, 0, stream>>>(wd, Wbuf, 2097152);
    gemm_bt<0, 1><<<dim3(16, 32), 256, 0, stream>>>(mb, Wbuf, (float*)d_out, x2, 2048, 8192);
}

// Round 4
// 1063.524 us; speedup vs baseline: 1.2820x; 1.0863x over previous
//
#include <hip/hip_runtime.h>
#include <hip/hip_bf16.h>

#define HID 2048
#define NH 16
#define HD 128
#define INTER 8192
#define SS 2048

typedef unsigned short u16;
typedef __attribute__((ext_vector_type(8))) short short8;
typedef __attribute__((ext_vector_type(4))) float f32x4;

__device__ __forceinline__ float bf2f(u16 u) {
    unsigned v = ((unsigned)u) << 16; float f; __builtin_memcpy(&f, &v, 4); return f;
}
__device__ __forceinline__ u16 f2bf(float f) {
    unsigned u; __builtin_memcpy(&u, &f, 4);
    u = u + 0x7FFFu + ((u >> 16) & 1u);   // RNE
    return (u16)(u >> 16);
}

typedef const __attribute__((address_space(1))) void* gas_t;
typedef __attribute__((address_space(3))) void* las_t;
__device__ __forceinline__ void gll16(const void* g, void* l) {
    __builtin_amdgcn_global_load_lds((gas_t)g, (las_t)l, 16, 0, 0);
}

// ---------------- elementwise / prep kernels ----------------

__global__ __launch_bounds__(256) void cast_f32_bf16_kernel(
    const float* __restrict__ src, u16* __restrict__ dst, int n8) {
    int gid = blockIdx.x * 256 + threadIdx.x;
    if (gid >= n8) return;
    const float4* s = (const float4*)src + (size_t)gid * 2;
    float4 a = s[0], b = s[1];
    short8 o;
    o[0] = (short)f2bf(a.x); o[1] = (short)f2bf(a.y); o[2] = (short)f2bf(a.z); o[3] = (short)f2bf(a.w);
    o[4] = (short)f2bf(b.x); o[5] = (short)f2bf(b.y); o[6] = (short)f2bf(b.z); o[7] = (short)f2bf(b.w);
    *((short8*)dst + gid) = o;
}

__global__ __launch_bounds__(256) void trig_kernel(float2* __restrict__ cs) {
    int id = blockIdx.x * 256 + threadIdx.x;   // < 2048*64
    int s = id >> 6, d = id & 63;
    float freq = expf(-(float)(2 * d) * (1.0f / (float)HD) * 9.210340371976184f); // ln(10000)
    float ang = (float)s * freq;
    cs[id] = make_float2(cosf(ang), sinf(ang));
}

__global__ __launch_bounds__(256) void ln_kernel(
    const float* __restrict__ X, const float* __restrict__ W, const float* __restrict__ Bv,
    u16* __restrict__ out) {
    const int row = blockIdx.x, tid = threadIdx.x;
    const float* xr = X + (size_t)row * HID;
    float4 v0 = ((const float4*)xr)[tid * 2];
    float4 v1 = ((const float4*)xr)[tid * 2 + 1];
    float e[8] = {v0.x, v0.y, v0.z, v0.w, v1.x, v1.y, v1.z, v1.w};
    float s = 0.f, ss2 = 0.f;
#pragma unroll
    for (int i = 0; i < 8; ++i) { s += e[i]; ss2 += e[i] * e[i]; }
#pragma unroll
    for (int m = 1; m < 64; m <<= 1) { s += __shfl_xor(s, m, 64); ss2 += __shfl_xor(ss2, m, 64); }
    __shared__ float red[8];
    if ((tid & 63) == 0) { red[tid >> 6] = s; red[4 + (tid >> 6)] = ss2; }
    __syncthreads();
    s = red[0] + red[1] + red[2] + red[3];
    ss2 = red[4] + red[5] + red[6] + red[7];
    float mean = s * (1.0f / HID);
    float var = ss2 * (1.0f / HID) - mean * mean;
    float rstd = rsqrtf(var + 1e-5f);
    float4 w0 = ((const float4*)W)[tid * 2], w1 = ((const float4*)W)[tid * 2 + 1];
    float4 b0 = ((const float4*)Bv)[tid * 2], b1 = ((const float4*)Bv)[tid * 2 + 1];
    float wv[8] = {w0.x, w0.y, w0.z, w0.w, w1.x, w1.y, w1.z, w1.w};
    float bv[8] = {b0.x, b0.y, b0.z, b0.w, b1.x, b1.y, b1.z, b1.w};
    short8 o;
#pragma unroll
    for (int i = 0; i < 8; ++i) o[i] = (short)f2bf((e[i] - mean) * rstd * wv[i] + bv[i]);
    *((short8*)(out + (size_t)row * HID) + tid) = o;
}

// RoPE on bf16 input (row stride 6144: reads q or k slice of fused qkv buffer)
__global__ __launch_bounds__(256) void rope_kernel(
    const u16* __restrict__ src, u16* __restrict__ dst, const float2* __restrict__ cs) {
    int gid = blockIdx.x * 256 + threadIdx.x;   // < 4096*16*64
    int d = gid & 63;
    int rh = gid >> 6;
    int h = rh & (NH - 1);
    int row = rh >> 4;               // b*2048+s
    int s = row & (SS - 1);
    unsigned pair = *(const unsigned*)(src + (size_t)row * 6144 + h * HD + 2 * d);
    float x1 = bf2f((u16)(pair & 0xFFFFu));
    float x2 = bf2f((u16)(pair >> 16));
    float2 t = cs[s * 64 + d];
    u16* q = dst + (size_t)row * HID + h * HD;
    q[d] = f2bf(x1 * t.x - x2 * t.y);
    q[64 + d] = f2bf(x1 * t.y + x2 * t.x);
}

// ---------------- GEMM: C[.,.] = A[M,K] * B[N,K]^T (bf16 in, fp32 acc) ----------------
// m97 structure: 128x128 tile, BK=32, 4 waves (each 64x64), global_load_lds width=16,
// staging-side pre-swizzle of the global source (rule #21: swizzle both sides or neither).

template <int OUT_BF16, int RESID>
__global__ __launch_bounds__(256) void gemm_bt(
    const u16* __restrict__ A, const u16* __restrict__ B,
    void* __restrict__ C, const float* __restrict__ resid,
    int ldc, int K) {
    __shared__ u16 As[128 * 32];
    __shared__ u16 Bs[128 * 32];
    const int tid = threadIdx.x;
    const int lane = tid & 63;
    const int wid = tid >> 6;
    const int lrow = lane & 15, lg = lane >> 4;
    const int m0 = blockIdx.y * 128, n0 = blockIdx.x * 128;
    const int wr = (wid >> 1) * 64, wn = (wid & 1) * 64;

    const int c0 = tid, c1 = tid + 256;
    const int r0 = c0 >> 2, k0c = ((c0 & 3) ^ ((c0 >> 3) & 3)) * 8;
    const int r1 = c1 >> 2, k1c = ((c1 & 3) ^ ((c1 >> 3) & 3)) * 8;
    const u16* Ag0 = A + (size_t)(m0 + r0) * K + k0c;
    const u16* Ag1 = A + (size_t)(m0 + r1) * K + k1c;
    const u16* Bg0 = B + (size_t)(n0 + r0) * K + k0c;
    const u16* Bg1 = B + (size_t)(n0 + r1) * K + k1c;
    u16* Al0 = &As[c0 * 8]; u16* Al1 = &As[c1 * 8];
    u16* Bl0 = &Bs[c0 * 8]; u16* Bl1 = &Bs[c1 * 8];

    f32x4 acc[4][4] = {};

    for (int kk = 0; kk < K; kk += 32) {
        __syncthreads();
        gll16(Ag0 + kk, Al0);
        gll16(Ag1 + kk, Al1);
        gll16(Bg0 + kk, Bl0);
        gll16(Bg1 + kk, Bl1);
        __syncthreads();
        short8 af[4], bfr[4];
#pragma unroll
        for (int m = 0; m < 4; ++m) {
            int row = wr + m * 16 + lrow;
            af[m] = *(const short8*)&As[row * 32 + (lg ^ ((row >> 1) & 3)) * 8];
        }
#pragma unroll
        for (int n = 0; n < 4; ++n) {
            int row = wn + n * 16 + lrow;
            bfr[n] = *(const short8*)&Bs[row * 32 + (lg ^ ((row >> 1) & 3)) * 8];
        }
#pragma unroll
        for (int m = 0; m < 4; ++m)
#pragma unroll
            for (int n = 0; n < 4; ++n)
                acc[m][n] = __builtin_amdgcn_mfma_f32_16x16x32_bf16(af[m], bfr[n], acc[m][n], 0, 0, 0);
    }

#pragma unroll
    for (int m = 0; m < 4; ++m)
#pragma unroll
        for (int n = 0; n < 4; ++n)
#pragma unroll
            for (int j = 0; j < 4; ++j) {
                int gm = m0 + wr + m * 16 + 4 * lg + j;
                int gn = n0 + wn + n * 16 + lrow;
                float v = acc[m][n][j];
                if (RESID) v += resid[(size_t)gm * ldc + gn];
                if (OUT_BF16) ((u16*)C)[(size_t)gm * ldc + gn] = f2bf(v);
                else ((float*)C)[(size_t)gm * ldc + gn] = v;
            }
}

// Fused gate/up GEMM + SiLU. 128x64-per-matrix tile (grid N/64 x M/128).
__global__ __launch_bounds__(256) void gemm_gu(
    const u16* __restrict__ A, const u16* __restrict__ Bg, const u16* __restrict__ Bu,
    u16* __restrict__ C, int ldc, int K) {
    __shared__ u16 As[128 * 32];
    __shared__ u16 Gs[64 * 32];
    __shared__ u16 Us[64 * 32];
    const int tid = threadIdx.x;
    const int lane = tid & 63;
    const int wid = tid >> 6;
    const int lrow = lane & 15, lg = lane >> 4;
    const int m0 = blockIdx.y * 128, n0 = blockIdx.x * 64;
    const int wr = (wid >> 1) * 64, wn = (wid & 1) * 32;

    const int c0 = tid, c1 = tid + 256;
    const int ra0 = c0 >> 2, ka0 = ((c0 & 3) ^ ((c0 >> 3) & 3)) * 8;
    const int ra1 = c1 >> 2, ka1 = ((c1 & 3) ^ ((c1 >> 3) & 3)) * 8;
    const int rg = tid >> 2, kg = ((tid & 3) ^ ((tid >> 3) & 3)) * 8;
    const u16* Ag0 = A + (size_t)(m0 + ra0) * K + ka0;
    const u16* Ag1 = A + (size_t)(m0 + ra1) * K + ka1;
    const u16* Gg = Bg + (size_t)(n0 + rg) * K + kg;
    const u16* Ug = Bu + (size_t)(n0 + rg) * K + kg;
    u16* Al0 = &As[c0 * 8]; u16* Al1 = &As[c1 * 8];
    u16* Gl = &Gs[tid * 8]; u16* Ul = &Us[tid * 8];

    f32x4 accg[4][2] = {};
    f32x4 accu[4][2] = {};

    for (int kk = 0; kk < K; kk += 32) {
        __syncthreads();
        gll16(Ag0 + kk, Al0);
        gll16(Ag1 + kk, Al1);
        gll16(Gg + kk, Gl);
        gll16(Ug + kk, Ul);
        __syncthreads();
        short8 af[4], gf[2], uf[2];
#pragma unroll
        for (int m = 0; m < 4; ++m) {
            int row = wr + m * 16 + lrow;
            af[m] = *(const short8*)&As[row * 32 + (lg ^ ((row >> 1) & 3)) * 8];
        }
#pragma unroll
        for (int n = 0; n < 2; ++n) {
            int row = wn + n * 16 + lrow;
            gf[n] = *(const short8*)&Gs[row * 32 + (lg ^ ((row >> 1) & 3)) * 8];
            uf[n] = *(const short8*)&Us[row * 32 + (lg ^ ((row >> 1) & 3)) * 8];
        }
#pragma unroll
        for (int m = 0; m < 4; ++m)
#pragma unroll
            for (int n = 0; n < 2; ++n) {
                accg[m][n] = __builtin_amdgcn_mfma_f32_16x16x32_bf16(af[m], gf[n], accg[m][n], 0, 0, 0);
                accu[m][n] = __builtin_amdgcn_mfma_f32_16x16x32_bf16(af[m], uf[n], accu[m][n], 0, 0, 0);
            }
    }

#pragma unroll
    for (int m = 0; m < 4; ++m)
#pragma unroll
        for (int n = 0; n < 2; ++n)
#pragma unroll
            for (int j = 0; j < 4; ++j) {
                int gm = m0 + wr + m * 16 + 4 * lg + j;
                int gn = n0 + wn + n * 16 + lrow;
                float g = accg[m][n][j];
                float u = accu[m][n][j];
                float v = g / (1.f + __expf(-g)) * u;
                C[(size_t)gm * ldc + gn] = f2bf(v);
            }
}

// ---------------- flash attention (causal), 64-row Q tiles, 4 waves ----------------
// Heavy-first q-tile order (tail fix) + T14 register prefetch of next K/V tile
// (global loads issued during softmax/PV, written to LDS at next loop top).

__global__ __launch_bounds__(256) void attn_kernel(
    const u16* __restrict__ Q, const u16* __restrict__ K, const u16* __restrict__ V,
    u16* __restrict__ O, int vstride) {
    const int bh = blockIdx.y;
    const int b = bh >> 4, h = bh & 15;
    const int q0 = ((int)gridDim.x - 1 - (int)blockIdx.x) * 64;   // heavy-first
    const int tid = threadIdx.x, wid = tid >> 6, lane = tid & 63;
    const int lrow = lane & 15, lg = lane >> 4;

    __shared__ u16 Ks[64 * 128];     // swizzled: byte = r*256 + 2*d ^ ((r&7)<<4)
    __shared__ u16 Vt[128 * 64];     // transposed: byte = d*128 + 2*k ^ ((d&7)<<4)
    __shared__ u16 Ps[4][16 * 64];   // per-wave P (wave-private; no barrier needed)

    const int qrow = q0 + wid * 16;
    short8 qf[4];
    {
        const u16* Qb = Q + ((size_t)(b * SS + qrow + lrow)) * HID + h * HD;
#pragma unroll
        for (int kc = 0; kc < 4; ++kc) qf[kc] = *(const short8*)(Qb + kc * 32 + lg * 8);
    }

    // staging mapping: K slot i -> row kr+16i, cols kdc..kdc+7
    //                  V slot i -> row (tid&63), cols vdc+32i..+7
    const int kr = tid >> 4, kdc = (tid & 15) * 8;
    const int vr = tid & 63, vdc = (tid >> 6) * 8;
    const u16* Kp = K + ((size_t)(b * SS + kr)) * HID + h * HD + kdc;
    const u16* Vp = V + ((size_t)(b * SS + vr)) * vstride + h * HD + vdc;

    short8 kpre[4], vpre[4];
#pragma unroll
    for (int i = 0; i < 4; ++i) kpre[i] = *(const short8*)(Kp + (size_t)(16 * i) * HID);
#pragma unroll
    for (int i = 0; i < 4; ++i) vpre[i] = *(const short8*)(Vp + 32 * i);

    f32x4 oacc[8] = {};
    float mrun[4] = {-3e38f, -3e38f, -3e38f, -3e38f};
    float lrun[4] = {0.f, 0.f, 0.f, 0.f};
    const float scale = 0.08838834764831845f;   // 1/sqrt(128)

    for (int j0 = 0; j0 <= q0; j0 += 64) {
        __syncthreads();                        // prev iter's LDS readers done
#pragma unroll
        for (int i = 0; i < 4; ++i) {           // K: vector write, swizzled
            int r = kr + 16 * i;
            *(short8*)((char*)Ks + ((r * 256 + kdc * 2) ^ ((r & 7) << 4))) = kpre[i];
        }
#pragma unroll
        for (int i = 0; i < 4; ++i) {           // V: transpose scatter
            int dc = vdc + 32 * i;
#pragma unroll
            for (int jj = 0; jj < 8; ++jj) {
                int d = dc + jj;
                *(u16*)((char*)Vt + ((d * 128 + 2 * vr) ^ ((d & 7) << 4))) = (u16)vpre[i][jj];
            }
        }
        __syncthreads();

        f32x4 sacc[4] = {};
#pragma unroll
        for (int n = 0; n < 4; ++n) {
#pragma unroll
            for (int kc = 0; kc < 4; ++kc) {
                int r = n * 16 + lrow;
                short8 kf = *(const short8*)((const char*)Ks +
                            ((r * 256 + (kc * 32 + lg * 8) * 2) ^ ((r & 7) << 4)));
                sacc[n] = __builtin_amdgcn_mfma_f32_16x16x32_bf16(qf[kc], kf, sacc[n], 0, 0, 0);
            }
        }

        const bool diag = (j0 == q0);
        float pm[4] = {-3e38f, -3e38f, -3e38f, -3e38f};
#pragma unroll
        for (int n = 0; n < 4; ++n)
#pragma unroll
            for (int j = 0; j < 4; ++j) {
                float sv = sacc[n][j] * scale;
                if (diag && (n * 16 + lrow > wid * 16 + 4 * lg + j)) sv = -1e30f;
                sacc[n][j] = sv;
                pm[j] = fmaxf(pm[j], sv);
            }

        // prefetch next K/V tile into regs; latency hides under softmax+PV
        if (j0 < q0) {
            const u16* Kn = Kp + (size_t)(j0 + 64) * HID;
            const u16* Vn = Vp + (size_t)(j0 + 64) * vstride;
#pragma unroll
            for (int i = 0; i < 4; ++i) kpre[i] = *(const short8*)(Kn + (size_t)(16 * i) * HID);
#pragma unroll
            for (int i = 0; i < 4; ++i) vpre[i] = *(const short8*)(Vn + 32 * i);
        }

#pragma unroll
        for (int j = 0; j < 4; ++j)
#pragma unroll
            for (int m = 1; m < 16; m <<= 1) pm[j] = fmaxf(pm[j], __shfl_xor(pm[j], m, 64));

        float sf[4], rs[4];
#pragma unroll
        for (int j = 0; j < 4; ++j) {
            float mnew = fmaxf(mrun[j], pm[j]);
            sf[j] = __expf(mrun[j] - mnew);
            mrun[j] = mnew;
            rs[j] = 0.f;
        }
#pragma unroll
        for (int n = 0; n < 4; ++n)
#pragma unroll
            for (int j = 0; j < 4; ++j) {
                float p = __expf(sacc[n][j] - mrun[j]);
                sacc[n][j] = p;
                rs[j] += p;
            }
#pragma unroll
        for (int j = 0; j < 4; ++j) {
#pragma unroll
            for (int m = 1; m < 16; m <<= 1) rs[j] += __shfl_xor(rs[j], m, 64);
            lrun[j] = lrun[j] * sf[j] + rs[j];
        }
#pragma unroll
        for (int n = 0; n < 8; ++n)
#pragma unroll
            for (int j = 0; j < 4; ++j) oacc[n][j] *= sf[j];

#pragma unroll
        for (int n = 0; n < 4; ++n)
#pragma unroll
            for (int j = 0; j < 4; ++j) {
                int row = 4 * lg + j, col = n * 16 + lrow;
                *(u16*)((char*)&Ps[wid][0] + ((row * 128 + col * 2) ^ ((row & 7) << 4))) =
                    f2bf(sacc[n][j]);
            }
        // Ps is wave-private: same-wave ds_write->ds_read ordered by lgkmcnt, no barrier.
        short8 pf[2];
#pragma unroll
        for (int ks = 0; ks < 2; ++ks)
            pf[ks] = *(const short8*)((const char*)&Ps[wid][0] +
                     ((lrow * 128 + (ks * 32 + lg * 8) * 2) ^ ((lrow & 7) << 4)));
#pragma unroll
        for (int n = 0; n < 8; ++n) {
            int d = n * 16 + lrow;
#pragma unroll
            for (int ks = 0; ks < 2; ++ks) {
                short8 vf = *(const short8*)((const char*)Vt +
                            ((d * 128 + (ks * 32 + lg * 8) * 2) ^ ((d & 7) << 4)));
                oacc[n] = __builtin_amdgcn_mfma_f32_16x16x32_bf16(pf[ks], vf, oacc[n], 0, 0, 0);
            }
        }
    }

#pragma unroll
    for (int n = 0; n < 8; ++n)
#pragma unroll
        for (int j = 0; j < 4; ++j) {
            int row = qrow + 4 * lg + j;
            O[((size_t)(b * SS + row)) * HID + h * HD + n * 16 + lrow] =
                f2bf(oacc[n][j] / lrun[j]);
        }
}

// ---------------- launcher ----------------

extern "C" void kernel_launch(void* const* d_in, const int* in_sizes, int n_in,
                              void* d_out, int out_size, void* d_ws, size_t ws_size,
                              hipStream_t stream) {
    const float* x    = (const float*)d_in[0];
    const float* ln1w = (const float*)d_in[1];
    const float* ln1b = (const float*)d_in[2];
    const float* ln2w = (const float*)d_in[3];
    const float* ln2b = (const float*)d_in[4];
    const float* wq   = (const float*)d_in[5];
    const float* wk   = (const float*)d_in[6];
    const float* wv   = (const float*)d_in[7];
    const float* wo   = (const float*)d_in[8];
    const float* wg   = (const float*)d_in[9];
    const float* wu   = (const float*)d_in[10];
    const float* wd   = (const float*)d_in[11];

    char* ws = (char*)d_ws;
    // 177 MiB total footprint:
    u16*    Wbuf = (u16*)(ws);                       // 32 MiB, reused per-GEMM
    u16*    hb   = (u16*)(ws + (32UL << 20));        // 16 MiB  LN out (bf16)
    u16*    qkvb = (u16*)(ws + (48UL << 20));        // 48 MiB  QKV bf16 [4096][6144]
    u16*    qb   = (u16*)(ws + (96UL << 20));        // 16 MiB
    u16*    kb   = (u16*)(ws + (112UL << 20));       // 16 MiB
    u16*    ob   = (u16*)(ws + (128UL << 20));       // 16 MiB
    float*  x2   = (float*)(ws + (144UL << 20));     // 32 MiB  fp32 residual stream
    float2* cs   = (float2*)(ws + (176UL << 20));    // 1 MiB   rope cos/sin
    u16*    mb   = qkvb;                             // 64 MiB alias (qkvb+qb, both dead by MLP)

    trig_kernel<<<512, 256, 0, stream>>>(cs);
    ln_kernel<<<4096, 256, 0, stream>>>(x, ln1w, ln1b, hb);

    // QKV projection (weights cast just-in-time into Wbuf: [wq;wk;wv] = 24 MiB)
    cast_f32_bf16_kernel<<<2048, 256, 0, stream>>>(wq, Wbuf, 524288);
    cast_f32_bf16_kernel<<<2048, 256, 0, stream>>>(wk, Wbuf + 4194304, 524288);
    cast_f32_bf16_kernel<<<2048, 256, 0, stream>>>(wv, Wbuf + 8388608, 524288);
    gemm_bt<1, 0><<<dim3(48, 32), 256, 0, stream>>>(hb, Wbuf, qkvb, nullptr, 6144, 2048);

    rope_kernel<<<16384, 256, 0, stream>>>(qkvb, qb, cs);
    rope_kernel<<<16384, 256, 0, stream>>>(qkvb + 2048, kb, cs);
    attn_kernel<<<dim3(32, 32), 256, 0, stream>>>(qb, kb, qkvb + 4096, ob, 6144);

    // O projection + residual (fp32 out)
    cast_f32_bf16_kernel<<<2048, 256, 0, stream>>>(wo, Wbuf, 524288);
    gemm_bt<0, 1><<<dim3(16, 32), 256, 0, stream>>>(ob, Wbuf, x2, x, 2048, 2048);

    ln_kernel<<<4096, 256, 0, stream>>>(x2, ln2w, ln2b, hb);

    // MLP gate/up in two 4096-column halves (SiLU fused in epilogue)
    for (int h = 0; h < 2; ++h) {
        cast_f32_bf16_kernel<<<4096, 256, 0, stream>>>(wg + (size_t)h * 8388608, Wbuf, 1048576);
        cast_f32_bf16_kernel<<<4096, 256, 0, stream>>>(wu + (size_t)h * 8388608, Wbuf + 8388608, 1048576);
        gemm_gu<<<dim3(64, 32), 256, 0, stream>>>(hb, Wbuf, Wbuf + 8388608,
                                                  mb + h * 4096, 8192, 2048);
    }

    // Down projection + residual -> fp32 d_out
    cast_f32_bf16_kernel<<<8192, 256, 0, stream>>>(wd, Wbuf, 2097152);
    gemm_bt<0, 1><<<dim3(16, 32), 256, 0, stream>>>(mb, Wbuf, (float*)d_out, x2, 2048, 8192);
}

// Round 6
// 950.002 us; speedup vs baseline: 1.4352x; 1.1195x over previous
//
#include <hip/hip_runtime.h>
#include <hip/hip_bf16.h>

#define HID 2048
#define NH 16
#define HD 128
#define INTER 8192
#define SS 2048

typedef unsigned short u16;
typedef __attribute__((ext_vector_type(8))) short short8;
typedef __attribute__((ext_vector_type(4))) float f32x4;

__device__ __forceinline__ float bf2f(u16 u) {
    unsigned v = ((unsigned)u) << 16; float f; __builtin_memcpy(&f, &v, 4); return f;
}
__device__ __forceinline__ u16 f2bf(float f) {
    unsigned u; __builtin_memcpy(&u, &f, 4);
    u = u + 0x7FFFu + ((u >> 16) & 1u);   // RNE
    return (u16)(u >> 16);
}

typedef const __attribute__((address_space(1))) void* gas_t;
typedef __attribute__((address_space(3))) void* las_t;
__device__ __forceinline__ void gll16(const void* g, void* l) {
    __builtin_amdgcn_global_load_lds((gas_t)g, (las_t)l, 16, 0, 0);
}

// ---------------- elementwise / prep kernels ----------------

__global__ __launch_bounds__(256) void cast_f32_bf16_kernel(
    const float* __restrict__ src, u16* __restrict__ dst, int n8) {
    int gid = blockIdx.x * 256 + threadIdx.x;
    if (gid >= n8) return;
    const float4* s = (const float4*)src + (size_t)gid * 2;
    float4 a = s[0], b = s[1];
    short8 o;
    o[0] = (short)f2bf(a.x); o[1] = (short)f2bf(a.y); o[2] = (short)f2bf(a.z); o[3] = (short)f2bf(a.w);
    o[4] = (short)f2bf(b.x); o[5] = (short)f2bf(b.y); o[6] = (short)f2bf(b.z); o[7] = (short)f2bf(b.w);
    *((short8*)dst + gid) = o;
}

__global__ __launch_bounds__(256) void trig_kernel(float2* __restrict__ cs) {
    int id = blockIdx.x * 256 + threadIdx.x;   // < 2048*64
    int s = id >> 6, d = id & 63;
    float freq = expf(-(float)(2 * d) * (1.0f / (float)HD) * 9.210340371976184f); // ln(10000)
    float ang = (float)s * freq;
    cs[id] = make_float2(cosf(ang), sinf(ang));
}

__global__ __launch_bounds__(256) void ln_kernel(
    const float* __restrict__ X, const float* __restrict__ W, const float* __restrict__ Bv,
    u16* __restrict__ out) {
    const int row = blockIdx.x, tid = threadIdx.x;
    const float* xr = X + (size_t)row * HID;
    float4 v0 = ((const float4*)xr)[tid * 2];
    float4 v1 = ((const float4*)xr)[tid * 2 + 1];
    float e[8] = {v0.x, v0.y, v0.z, v0.w, v1.x, v1.y, v1.z, v1.w};
    float s = 0.f, ss2 = 0.f;
#pragma unroll
    for (int i = 0; i < 8; ++i) { s += e[i]; ss2 += e[i] * e[i]; }
#pragma unroll
    for (int m = 1; m < 64; m <<= 1) { s += __shfl_xor(s, m, 64); ss2 += __shfl_xor(ss2, m, 64); }
    __shared__ float red[8];
    if ((tid & 63) == 0) { red[tid >> 6] = s; red[4 + (tid >> 6)] = ss2; }
    __syncthreads();
    s = red[0] + red[1] + red[2] + red[3];
    ss2 = red[4] + red[5] + red[6] + red[7];
    float mean = s * (1.0f / HID);
    float var = ss2 * (1.0f / HID) - mean * mean;
    float rstd = rsqrtf(var + 1e-5f);
    float4 w0 = ((const float4*)W)[tid * 2], w1 = ((const float4*)W)[tid * 2 + 1];
    float4 b0 = ((const float4*)Bv)[tid * 2], b1 = ((const float4*)Bv)[tid * 2 + 1];
    float wv[8] = {w0.x, w0.y, w0.z, w0.w, w1.x, w1.y, w1.z, w1.w};
    float bv[8] = {b0.x, b0.y, b0.z, b0.w, b1.x, b1.y, b1.z, b1.w};
    short8 o;
#pragma unroll
    for (int i = 0; i < 8; ++i) o[i] = (short)f2bf((e[i] - mean) * rstd * wv[i] + bv[i]);
    *((short8*)(out + (size_t)row * HID) + tid) = o;
}

// RoPE on bf16 input (row stride 6144: reads q or k slice of fused qkv buffer)
__global__ __launch_bounds__(256) void rope_kernel(
    const u16* __restrict__ src, u16* __restrict__ dst, const float2* __restrict__ cs) {
    int gid = blockIdx.x * 256 + threadIdx.x;   // < 4096*16*64
    int d = gid & 63;
    int rh = gid >> 6;
    int h = rh & (NH - 1);
    int row = rh >> 4;               // b*2048+s
    int s = row & (SS - 1);
    unsigned pair = *(const unsigned*)(src + (size_t)row * 6144 + h * HD + 2 * d);
    float x1 = bf2f((u16)(pair & 0xFFFFu));
    float x2 = bf2f((u16)(pair >> 16));
    float2 t = cs[s * 64 + d];
    u16* q = dst + (size_t)row * HID + h * HD;
    q[d] = f2bf(x1 * t.x - x2 * t.y);
    q[64 + d] = f2bf(x1 * t.y + x2 * t.x);
}

// ---------------- GEMM 256x128 phase-scheduled (T1+T2+T4+T5) ----------------
// C[M,N] = A[M,K] * B[N,K]^T. BM=256, BN=128, BK=64, 512 threads (8 waves, 2Mx4N,
// per-wave 128x32). 3 LDS slots; tile t computed while t+1 landed and t+2 staged.
// RACE-FREE schedule (one barrier per tile):
//   vmcnt(6|0) ; s_barrier ; stage(t+2) ; readsA ; MFMA-A ; readsB ; MFMA-B
// WAR safety: slot (t+2)%3's last reads (phase-B of t-1) are CONSUMED by that
// wave's MFMA-B (compiler lgkmcnt) before it reaches iter-t's barrier; stage is
// issued only after that barrier. RAW: vmcnt(6)+barrier => all waves' tile-t
// loads landed before any read. Stage slot (t-1)%3 is disjoint from read slot.
template <int OUT_BF16, int RESID>
__global__ __launch_bounds__(512, 2) void gemm256(
    const u16* __restrict__ A, const u16* __restrict__ B,
    void* __restrict__ C, const float* __restrict__ resid,
    int ldc, int K, int nx) {
    extern __shared__ u16 dyn[];    // 3 slots x (A 256x64 + B 128x64) u16
    const int tid = threadIdx.x;
    const int lane = tid & 63, wid = tid >> 6;
    const int lrow = lane & 15, lg = lane >> 4;
    const int wm = wid >> 2, wn = wid & 3;

    // T1: bijective XCD remap (gridDim.x % 8 == 0 at all call sites)
    const int orig = blockIdx.x;
    const int wg = (orig & 7) * ((int)gridDim.x >> 3) + (orig >> 3);
    const int bx = wg % nx, by = wg / nx;
    const int m0 = by * 256, n0 = bx * 128;

    // staging: LDS linear chunk (r,p) holds global chunk p^(r&7) (pre-swizzled src)
    const u16* ga[4]; const u16* gb[2];
    int lA[4], lB[2];
#pragma unroll
    for (int i = 0; i < 4; ++i) {
        int c = tid + 512 * i, r = c >> 3, kc = (c & 7) ^ (r & 7);
        ga[i] = A + (size_t)(m0 + r) * K + kc * 8;
        lA[i] = c * 8;
    }
#pragma unroll
    for (int i = 0; i < 2; ++i) {
        int c = tid + 512 * i, r = c >> 3, kc = (c & 7) ^ (r & 7);
        gb[i] = B + (size_t)(n0 + r) * K + kc * 8;
        lB[i] = 16384 + c * 8;
    }
    const int NT = K >> 6;

    auto stage = [&](int slot) {
        u16* s = dyn + slot * 24576;
#pragma unroll
        for (int i = 0; i < 4; ++i) { gll16(ga[i], s + lA[i]); ga[i] += 64; }
#pragma unroll
        for (int i = 0; i < 2; ++i) { gll16(gb[i], s + lB[i]); gb[i] += 64; }
    };

    stage(0);
    stage(1);

    const int rowAb = (wm * 128 + lrow) * 64;          // u16 offset
    const int rowBb = 16384 + (wn * 32 + lrow) * 64;
    const int cOff = (lg ^ (lrow & 7)) * 8;            // ks=1: ^32

    f32x4 acc[8][2] = {};
    int slot = 0;
    for (int t = 0; t < NT; ++t) {
        if (t + 1 < NT) asm volatile("s_waitcnt vmcnt(6)" ::: "memory");
        else            asm volatile("s_waitcnt vmcnt(0)" ::: "memory");
        __builtin_amdgcn_s_barrier();          // all waves: tile t landed; slot (t-1)'s reads consumed
        __builtin_amdgcn_sched_barrier(0);
        if (t + 2 < NT) stage(slot == 0 ? 2 : slot - 1);   // slot (t+2)%3

        const u16* sb = dyn + slot * 24576;
        short8 af[4][2], bf[2][2];
#pragma unroll
        for (int m = 0; m < 4; ++m) {
            af[m][0] = *(const short8*)(sb + rowAb + m * 1024 + cOff);
            af[m][1] = *(const short8*)(sb + rowAb + m * 1024 + (cOff ^ 32));
        }
#pragma unroll
        for (int n = 0; n < 2; ++n) {
            bf[n][0] = *(const short8*)(sb + rowBb + n * 1024 + cOff);
            bf[n][1] = *(const short8*)(sb + rowBb + n * 1024 + (cOff ^ 32));
        }
        __builtin_amdgcn_s_setprio(1);
#pragma unroll
        for (int m = 0; m < 4; ++m)
#pragma unroll
            for (int n = 0; n < 2; ++n) {
                acc[m][n] = __builtin_amdgcn_mfma_f32_16x16x32_bf16(af[m][0], bf[n][0], acc[m][n], 0, 0, 0);
                acc[m][n] = __builtin_amdgcn_mfma_f32_16x16x32_bf16(af[m][1], bf[n][1], acc[m][n], 0, 0, 0);
            }
        __builtin_amdgcn_s_setprio(0);
#pragma unroll
        for (int m = 0; m < 4; ++m) {
            af[m][0] = *(const short8*)(sb + rowAb + (m + 4) * 1024 + cOff);
            af[m][1] = *(const short8*)(sb + rowAb + (m + 4) * 1024 + (cOff ^ 32));
        }
        __builtin_amdgcn_s_setprio(1);
#pragma unroll
        for (int m = 0; m < 4; ++m)
#pragma unroll
            for (int n = 0; n < 2; ++n) {
                acc[m + 4][n] = __builtin_amdgcn_mfma_f32_16x16x32_bf16(af[m][0], bf[n][0], acc[m + 4][n], 0, 0, 0);
                acc[m + 4][n] = __builtin_amdgcn_mfma_f32_16x16x32_bf16(af[m][1], bf[n][1], acc[m + 4][n], 0, 0, 0);
            }
        __builtin_amdgcn_s_setprio(0);
        slot = slot == 2 ? 0 : slot + 1;
    }

#pragma unroll
    for (int m = 0; m < 8; ++m)
#pragma unroll
        for (int n = 0; n < 2; ++n)
#pragma unroll
            for (int j = 0; j < 4; ++j) {
                int gm = m0 + wm * 128 + m * 16 + 4 * lg + j;
                int gn = n0 + wn * 32 + n * 16 + lrow;
                float v = acc[m][n][j];
                if (RESID) v += resid[(size_t)gm * ldc + gn];
                if (OUT_BF16) ((u16*)C)[(size_t)gm * ldc + gn] = f2bf(v);
                else ((float*)C)[(size_t)gm * ldc + gn] = v;
            }
}

// Fused gate/up GEMM + SiLU. 128x64-per-matrix tile; 1-D grid with T1 remap.
__global__ __launch_bounds__(256) void gemm_gu(
    const u16* __restrict__ A, const u16* __restrict__ Bg, const u16* __restrict__ Bu,
    u16* __restrict__ C, int ldc, int K, int nx) {
    __shared__ u16 As[128 * 32];
    __shared__ u16 Gs[64 * 32];
    __shared__ u16 Us[64 * 32];
    const int tid = threadIdx.x;
    const int lane = tid & 63;
    const int wid = tid >> 6;
    const int lrow = lane & 15, lg = lane >> 4;
    const int orig = blockIdx.x;
    const int wg = (orig & 7) * ((int)gridDim.x >> 3) + (orig >> 3);
    const int m0 = (wg / nx) * 128, n0 = (wg % nx) * 64;
    const int wr = (wid >> 1) * 64, wn = (wid & 1) * 32;

    const int c0 = tid, c1 = tid + 256;
    const int ra0 = c0 >> 2, ka0 = ((c0 & 3) ^ ((c0 >> 3) & 3)) * 8;
    const int ra1 = c1 >> 2, ka1 = ((c1 & 3) ^ ((c1 >> 3) & 3)) * 8;
    const int rg = tid >> 2, kg = ((tid & 3) ^ ((tid >> 3) & 3)) * 8;
    const u16* Ag0 = A + (size_t)(m0 + ra0) * K + ka0;
    const u16* Ag1 = A + (size_t)(m0 + ra1) * K + ka1;
    const u16* Gg = Bg + (size_t)(n0 + rg) * K + kg;
    const u16* Ug = Bu + (size_t)(n0 + rg) * K + kg;
    u16* Al0 = &As[c0 * 8]; u16* Al1 = &As[c1 * 8];
    u16* Gl = &Gs[tid * 8]; u16* Ul = &Us[tid * 8];

    f32x4 accg[4][2] = {};
    f32x4 accu[4][2] = {};

    for (int kk = 0; kk < K; kk += 32) {
        __syncthreads();
        gll16(Ag0 + kk, Al0);
        gll16(Ag1 + kk, Al1);
        gll16(Gg + kk, Gl);
        gll16(Ug + kk, Ul);
        __syncthreads();
        short8 af[4], gf[2], uf[2];
#pragma unroll
        for (int m = 0; m < 4; ++m) {
            int row = wr + m * 16 + lrow;
            af[m] = *(const short8*)&As[row * 32 + (lg ^ ((row >> 1) & 3)) * 8];
        }
#pragma unroll
        for (int n = 0; n < 2; ++n) {
            int row = wn + n * 16 + lrow;
            gf[n] = *(const short8*)&Gs[row * 32 + (lg ^ ((row >> 1) & 3)) * 8];
            uf[n] = *(const short8*)&Us[row * 32 + (lg ^ ((row >> 1) & 3)) * 8];
        }
#pragma unroll
        for (int m = 0; m < 4; ++m)
#pragma unroll
            for (int n = 0; n < 2; ++n) {
                accg[m][n] = __builtin_amdgcn_mfma_f32_16x16x32_bf16(af[m], gf[n], accg[m][n], 0, 0, 0);
                accu[m][n] = __builtin_amdgcn_mfma_f32_16x16x32_bf16(af[m], uf[n], accu[m][n], 0, 0, 0);
            }
    }

#pragma unroll
    for (int m = 0; m < 4; ++m)
#pragma unroll
        for (int n = 0; n < 2; ++n)
#pragma unroll
            for (int j = 0; j < 4; ++j) {
                int gm = m0 + wr + m * 16 + 4 * lg + j;
                int gn = n0 + wn + n * 16 + lrow;
                float g = accg[m][n][j];
                float u = accu[m][n][j];
                float v = g / (1.f + __expf(-g)) * u;
                C[(size_t)gm * ldc + gn] = f2bf(v);
            }
}

// ---------------- flash attention (causal), 64-row Q tiles, 4 waves ----------------

__global__ __launch_bounds__(256) void attn_kernel(
    const u16* __restrict__ Q, const u16* __restrict__ K, const u16* __restrict__ V,
    u16* __restrict__ O, int vstride) {
    const int bh = blockIdx.y;
    const int b = bh >> 4, h = bh & 15;
    const int q0 = ((int)gridDim.x - 1 - (int)blockIdx.x) * 64;   // heavy-first
    const int tid = threadIdx.x, wid = tid >> 6, lane = tid & 63;
    const int lrow = lane & 15, lg = lane >> 4;

    __shared__ u16 Ks[64 * 128];
    __shared__ u16 Vt[128 * 64];
    __shared__ u16 Ps[4][16 * 64];

    const int qrow = q0 + wid * 16;
    short8 qf[4];
    {
        const u16* Qb = Q + ((size_t)(b * SS + qrow + lrow)) * HID + h * HD;
#pragma unroll
        for (int kc = 0; kc < 4; ++kc) qf[kc] = *(const short8*)(Qb + kc * 32 + lg * 8);
    }

    const int kr = tid >> 4, kdc = (tid & 15) * 8;
    const int vr = tid & 63, vdc = (tid >> 6) * 8;
    const u16* Kp = K + ((size_t)(b * SS + kr)) * HID + h * HD + kdc;
    const u16* Vp = V + ((size_t)(b * SS + vr)) * vstride + h * HD + vdc;

    short8 kpre[4], vpre[4];
#pragma unroll
    for (int i = 0; i < 4; ++i) kpre[i] = *(const short8*)(Kp + (size_t)(16 * i) * HID);
#pragma unroll
    for (int i = 0; i < 4; ++i) vpre[i] = *(const short8*)(Vp + 32 * i);

    f32x4 oacc[8] = {};
    float mrun[4] = {-3e38f, -3e38f, -3e38f, -3e38f};
    float lrun[4] = {0.f, 0.f, 0.f, 0.f};
    const float scale = 0.08838834764831845f;

    for (int j0 = 0; j0 <= q0; j0 += 64) {
        __syncthreads();
#pragma unroll
        for (int i = 0; i < 4; ++i) {
            int r = kr + 16 * i;
            *(short8*)((char*)Ks + ((r * 256 + kdc * 2) ^ ((r & 7) << 4))) = kpre[i];
        }
#pragma unroll
        for (int i = 0; i < 4; ++i) {
            int dc = vdc + 32 * i;
#pragma unroll
            for (int jj = 0; jj < 8; ++jj) {
                int d = dc + jj;
                *(u16*)((char*)Vt + ((d * 128 + 2 * vr) ^ ((d & 7) << 4))) = (u16)vpre[i][jj];
            }
        }
        __syncthreads();

        f32x4 sacc[4] = {};
#pragma unroll
        for (int n = 0; n < 4; ++n) {
#pragma unroll
            for (int kc = 0; kc < 4; ++kc) {
                int r = n * 16 + lrow;
                short8 kf = *(const short8*)((const char*)Ks +
                            ((r * 256 + (kc * 32 + lg * 8) * 2) ^ ((r & 7) << 4)));
                sacc[n] = __builtin_amdgcn_mfma_f32_16x16x32_bf16(qf[kc], kf, sacc[n], 0, 0, 0);
            }
        }

        const bool diag = (j0 == q0);
        float pm[4] = {-3e38f, -3e38f, -3e38f, -3e38f};
#pragma unroll
        for (int n = 0; n < 4; ++n)
#pragma unroll
            for (int j = 0; j < 4; ++j) {
                float sv = sacc[n][j] * scale;
                if (diag && (n * 16 + lrow > wid * 16 + 4 * lg + j)) sv = -1e30f;
                sacc[n][j] = sv;
                pm[j] = fmaxf(pm[j], sv);
            }

        if (j0 < q0) {
            const u16* Kn = Kp + (size_t)(j0 + 64) * HID;
            const u16* Vn = Vp + (size_t)(j0 + 64) * vstride;
#pragma unroll
            for (int i = 0; i < 4; ++i) kpre[i] = *(const short8*)(Kn + (size_t)(16 * i) * HID);
#pragma unroll
            for (int i = 0; i < 4; ++i) vpre[i] = *(const short8*)(Vn + 32 * i);
        }

#pragma unroll
        for (int j = 0; j < 4; ++j)
#pragma unroll
            for (int m = 1; m < 16; m <<= 1) pm[j] = fmaxf(pm[j], __shfl_xor(pm[j], m, 64));

        float sf[4], rs[4];
#pragma unroll
        for (int j = 0; j < 4; ++j) {
            float mnew = fmaxf(mrun[j], pm[j]);
            sf[j] = __expf(mrun[j] - mnew);
            mrun[j] = mnew;
            rs[j] = 0.f;
        }
#pragma unroll
        for (int n = 0; n < 4; ++n)
#pragma unroll
            for (int j = 0; j < 4; ++j) {
                float p = __expf(sacc[n][j] - mrun[j]);
                sacc[n][j] = p;
                rs[j] += p;
            }
#pragma unroll
        for (int j = 0; j < 4; ++j) {
#pragma unroll
            for (int m = 1; m < 16; m <<= 1) rs[j] += __shfl_xor(rs[j], m, 64);
            lrun[j] = lrun[j] * sf[j] + rs[j];
        }
#pragma unroll
        for (int n = 0; n < 8; ++n)
#pragma unroll
            for (int j = 0; j < 4; ++j) oacc[n][j] *= sf[j];

#pragma unroll
        for (int n = 0; n < 4; ++n)
#pragma unroll
            for (int j = 0; j < 4; ++j) {
                int row = 4 * lg + j, col = n * 16 + lrow;
                *(u16*)((char*)&Ps[wid][0] + ((row * 128 + col * 2) ^ ((row & 7) << 4))) =
                    f2bf(sacc[n][j]);
            }
        short8 pf[2];
#pragma unroll
        for (int ks = 0; ks < 2; ++ks)
            pf[ks] = *(const short8*)((const char*)&Ps[wid][0] +
                     ((lrow * 128 + (ks * 32 + lg * 8) * 2) ^ ((lrow & 7) << 4)));
#pragma unroll
        for (int n = 0; n < 8; ++n) {
            int d = n * 16 + lrow;
#pragma unroll
            for (int ks = 0; ks < 2; ++ks) {
                short8 vf = *(const short8*)((const char*)Vt +
                            ((d * 128 + (ks * 32 + lg * 8) * 2) ^ ((d & 7) << 4)));
                oacc[n] = __builtin_amdgcn_mfma_f32_16x16x32_bf16(pf[ks], vf, oacc[n], 0, 0, 0);
            }
        }
    }

#pragma unroll
    for (int n = 0; n < 8; ++n)
#pragma unroll
        for (int j = 0; j < 4; ++j) {
            int row = qrow + 4 * lg + j;
            O[((size_t)(b * SS + row)) * HID + h * HD + n * 16 + lrow] =
                f2bf(oacc[n][j] / lrun[j]);
        }
}

// ---------------- launcher ----------------

extern "C" void kernel_launch(void* const* d_in, const int* in_sizes, int n_in,
                              void* d_out, int out_size, void* d_ws, size_t ws_size,
                              hipStream_t stream) {
    const float* x    = (const float*)d_in[0];
    const float* ln1w = (const float*)d_in[1];
    const float* ln1b = (const float*)d_in[2];
    const float* ln2w = (const float*)d_in[3];
    const float* ln2b = (const float*)d_in[4];
    const float* wq   = (const float*)d_in[5];
    const float* wk   = (const float*)d_in[6];
    const float* wv   = (const float*)d_in[7];
    const float* wo   = (const float*)d_in[8];
    const float* wg   = (const float*)d_in[9];
    const float* wu   = (const float*)d_in[10];
    const float* wd   = (const float*)d_in[11];

    char* ws = (char*)d_ws;
    u16*    Wbuf = (u16*)(ws);                       // 32 MiB, reused per-GEMM
    u16*    hb   = (u16*)(ws + (32UL << 20));        // 16 MiB  LN out (bf16)
    u16*    qkvb = (u16*)(ws + (48UL << 20));        // 48 MiB  QKV bf16 [4096][6144]
    u16*    qb   = (u16*)(ws + (96UL << 20));        // 16 MiB
    u16*    kb   = (u16*)(ws + (112UL << 20));       // 16 MiB
    u16*    ob   = (u16*)(ws + (128UL << 20));       // 16 MiB
    float*  x2   = (float*)(ws + (144UL << 20));     // 32 MiB  fp32 residual stream
    float2* cs   = (float2*)(ws + (176UL << 20));    // 1 MiB   rope cos/sin
    u16*    mb   = qkvb;                             // 64 MiB alias

    trig_kernel<<<512, 256, 0, stream>>>(cs);
    ln_kernel<<<4096, 256, 0, stream>>>(x, ln1w, ln1b, hb);

    // QKV projection
    cast_f32_bf16_kernel<<<2048, 256, 0, stream>>>(wq, Wbuf, 524288);
    cast_f32_bf16_kernel<<<2048, 256, 0, stream>>>(wk, Wbuf + 4194304, 524288);
    cast_f32_bf16_kernel<<<2048, 256, 0, stream>>>(wv, Wbuf + 8388608, 524288);
    gemm256<1, 0><<<768, 512, 147456, stream>>>(hb, Wbuf, qkvb, nullptr, 6144, 2048, 48);

    rope_kernel<<<16384, 256, 0, stream>>>(qkvb, qb, cs);
    rope_kernel<<<16384, 256, 0, stream>>>(qkvb + 2048, kb, cs);
    attn_kernel<<<dim3(32, 32), 256, 0, stream>>>(qb, kb, qkvb + 4096, ob, 6144);

    // O projection + residual (fp32 out)
    cast_f32_bf16_kernel<<<2048, 256, 0, stream>>>(wo, Wbuf, 524288);
    gemm256<0, 1><<<256, 512, 147456, stream>>>(ob, Wbuf, x2, x, 2048, 2048, 16);

    ln_kernel<<<4096, 256, 0, stream>>>(x2, ln2w, ln2b, hb);

    // MLP gate/up in two 4096-column halves (SiLU fused in epilogue)
    for (int h = 0; h < 2; ++h) {
        cast_f32_bf16_kernel<<<4096, 256, 0, stream>>>(wg + (size_t)h * 8388608, Wbuf, 1048576);
        cast_f32_bf16_kernel<<<4096, 256, 0, stream>>>(wu + (size_t)h * 8388608, Wbuf + 8388608, 1048576);
        gemm_gu<<<2048, 256, 0, stream>>>(hb, Wbuf, Wbuf + 8388608,
                                          mb + h * 4096, 8192, 2048, 64);
    }

    // Down projection + residual -> fp32 d_out
    cast_f32_bf16_kernel<<<8192, 256, 0, stream>>>(wd, Wbuf, 2097152);
    gemm256<0, 1><<<256, 512, 147456, stream>>>(mb, Wbuf, (float*)d_out, x2, 2048, 8192, 16);
}

// Round 7
// 851.030 us; speedup vs baseline: 1.6022x; 1.1163x over previous
//
#include <hip/hip_runtime.h>
#include <hip/hip_bf16.h>

#define HID 2048
#define NH 16
#define HD 128
#define INTER 8192
#define SS 2048

typedef unsigned short u16;
typedef __attribute__((ext_vector_type(8))) short short8;
typedef __attribute__((ext_vector_type(4))) short short4v;
typedef __attribute__((ext_vector_type(4))) float f32x4;

__device__ __forceinline__ float bf2f(u16 u) {
    unsigned v = ((unsigned)u) << 16; float f; __builtin_memcpy(&f, &v, 4); return f;
}
__device__ __forceinline__ u16 f2bf(float f) {
    unsigned u; __builtin_memcpy(&u, &f, 4);
    u = u + 0x7FFFu + ((u >> 16) & 1u);   // RNE
    return (u16)(u >> 16);
}

typedef const __attribute__((address_space(1))) void* gas_t;
typedef __attribute__((address_space(3))) void* las_t;
__device__ __forceinline__ void gll16(const void* g, void* l) {
    __builtin_amdgcn_global_load_lds((gas_t)g, (las_t)l, 16, 0, 0);
}

// VALU-pipe cross-lane via DPP (replaces __shfl_xor's ds_swizzle on the DS pipe).
// Butterfly over each 16-lane row: quad_perm xor1 (0xB1), quad_perm xor2 (0x4E),
// row_half_mirror (0x141), row_mirror (0x140).
template <int CTRL>
__device__ __forceinline__ float dppf(float x) {
    union { float f; int i; } u; u.f = x;
    u.i = __builtin_amdgcn_update_dpp(u.i, u.i, CTRL, 0xf, 0xf, false);
    return u.f;
}
__device__ __forceinline__ float rmax16(float x) {
    x = fmaxf(x, dppf<0xB1>(x));
    x = fmaxf(x, dppf<0x4E>(x));
    x = fmaxf(x, dppf<0x141>(x));
    x = fmaxf(x, dppf<0x140>(x));
    return x;
}
__device__ __forceinline__ float rsum16(float x) {
    x = x + dppf<0xB1>(x);
    x = x + dppf<0x4E>(x);
    x = x + dppf<0x141>(x);
    x = x + dppf<0x140>(x);
    return x;
}

// ---------------- elementwise / prep kernels ----------------

__global__ __launch_bounds__(256) void cast_f32_bf16_kernel(
    const float* __restrict__ src, u16* __restrict__ dst, int n8) {
    int gid = blockIdx.x * 256 + threadIdx.x;
    if (gid >= n8) return;
    const float4* s = (const float4*)src + (size_t)gid * 2;
    float4 a = s[0], b = s[1];
    short8 o;
    o[0] = (short)f2bf(a.x); o[1] = (short)f2bf(a.y); o[2] = (short)f2bf(a.z); o[3] = (short)f2bf(a.w);
    o[4] = (short)f2bf(b.x); o[5] = (short)f2bf(b.y); o[6] = (short)f2bf(b.z); o[7] = (short)f2bf(b.w);
    *((short8*)dst + gid) = o;
}

__global__ __launch_bounds__(256) void trig_kernel(float2* __restrict__ cs) {
    int id = blockIdx.x * 256 + threadIdx.x;   // < 2048*64
    int s = id >> 6, d = id & 63;
    float freq = expf(-(float)(2 * d) * (1.0f / (float)HD) * 9.210340371976184f); // ln(10000)
    float ang = (float)s * freq;
    cs[id] = make_float2(cosf(ang), sinf(ang));
}

__global__ __launch_bounds__(256) void ln_kernel(
    const float* __restrict__ X, const float* __restrict__ W, const float* __restrict__ Bv,
    u16* __restrict__ out) {
    const int row = blockIdx.x, tid = threadIdx.x;
    const float* xr = X + (size_t)row * HID;
    float4 v0 = ((const float4*)xr)[tid * 2];
    float4 v1 = ((const float4*)xr)[tid * 2 + 1];
    float e[8] = {v0.x, v0.y, v0.z, v0.w, v1.x, v1.y, v1.z, v1.w};
    float s = 0.f, ss2 = 0.f;
#pragma unroll
    for (int i = 0; i < 8; ++i) { s += e[i]; ss2 += e[i] * e[i]; }
#pragma unroll
    for (int m = 1; m < 64; m <<= 1) { s += __shfl_xor(s, m, 64); ss2 += __shfl_xor(ss2, m, 64); }
    __shared__ float red[8];
    if ((tid & 63) == 0) { red[tid >> 6] = s; red[4 + (tid >> 6)] = ss2; }
    __syncthreads();
    s = red[0] + red[1] + red[2] + red[3];
    ss2 = red[4] + red[5] + red[6] + red[7];
    float mean = s * (1.0f / HID);
    float var = ss2 * (1.0f / HID) - mean * mean;
    float rstd = rsqrtf(var + 1e-5f);
    float4 w0 = ((const float4*)W)[tid * 2], w1 = ((const float4*)W)[tid * 2 + 1];
    float4 b0 = ((const float4*)Bv)[tid * 2], b1 = ((const float4*)Bv)[tid * 2 + 1];
    float wv[8] = {w0.x, w0.y, w0.z, w0.w, w1.x, w1.y, w1.z, w1.w};
    float bv[8] = {b0.x, b0.y, b0.z, b0.w, b1.x, b1.y, b1.z, b1.w};
    short8 o;
#pragma unroll
    for (int i = 0; i < 8; ++i) o[i] = (short)f2bf((e[i] - mean) * rstd * wv[i] + bv[i]);
    *((short8*)(out + (size_t)row * HID) + tid) = o;
}

// RoPE on bf16 input (row stride 6144) with output pre-scale (Q gets 1/sqrt(D))
__global__ __launch_bounds__(256) void rope_kernel(
    const u16* __restrict__ src, u16* __restrict__ dst, const float2* __restrict__ cs,
    float oscale) {
    int gid = blockIdx.x * 256 + threadIdx.x;   // < 4096*16*64
    int d = gid & 63;
    int rh = gid >> 6;
    int h = rh & (NH - 1);
    int row = rh >> 4;               // b*2048+s
    int s = row & (SS - 1);
    unsigned pair = *(const unsigned*)(src + (size_t)row * 6144 + h * HD + 2 * d);
    float x1 = bf2f((u16)(pair & 0xFFFFu));
    float x2 = bf2f((u16)(pair >> 16));
    float2 t = cs[s * 64 + d];
    u16* q = dst + (size_t)row * HID + h * HD;
    q[d] = f2bf((x1 * t.x - x2 * t.y) * oscale);
    q[64 + d] = f2bf((x1 * t.y + x2 * t.x) * oscale);
}

// ---------------- GEMM 256x128 phase-scheduled (T1+T2+T4+T5) ----------------
// Race-free schedule (validated r6): vmcnt(6|0); barrier; stage(t+2); readsA;
// MFMA-A; readsB; MFMA-B. 3 LDS slots.
template <int OUT_BF16, int RESID>
__global__ __launch_bounds__(512, 2) void gemm256(
    const u16* __restrict__ A, const u16* __restrict__ B,
    void* __restrict__ C, const float* __restrict__ resid,
    int ldc, int K, int nx) {
    extern __shared__ u16 dyn[];    // 3 slots x (A 256x64 + B 128x64) u16
    const int tid = threadIdx.x;
    const int lane = tid & 63, wid = tid >> 6;
    const int lrow = lane & 15, lg = lane >> 4;
    const int wm = wid >> 2, wn = wid & 3;

    const int orig = blockIdx.x;
    const int wg = (orig & 7) * ((int)gridDim.x >> 3) + (orig >> 3);
    const int bx = wg % nx, by = wg / nx;
    const int m0 = by * 256, n0 = bx * 128;

    const u16* ga[4]; const u16* gb[2];
    int lA[4], lB[2];
#pragma unroll
    for (int i = 0; i < 4; ++i) {
        int c = tid + 512 * i, r = c >> 3, kc = (c & 7) ^ (r & 7);
        ga[i] = A + (size_t)(m0 + r) * K + kc * 8;
        lA[i] = c * 8;
    }
#pragma unroll
    for (int i = 0; i < 2; ++i) {
        int c = tid + 512 * i, r = c >> 3, kc = (c & 7) ^ (r & 7);
        gb[i] = B + (size_t)(n0 + r) * K + kc * 8;
        lB[i] = 16384 + c * 8;
    }
    const int NT = K >> 6;

    auto stage = [&](int slot) {
        u16* s = dyn + slot * 24576;
#pragma unroll
        for (int i = 0; i < 4; ++i) { gll16(ga[i], s + lA[i]); ga[i] += 64; }
#pragma unroll
        for (int i = 0; i < 2; ++i) { gll16(gb[i], s + lB[i]); gb[i] += 64; }
    };

    stage(0);
    stage(1);

    const int rowAb = (wm * 128 + lrow) * 64;
    const int rowBb = 16384 + (wn * 32 + lrow) * 64;
    const int cOff = (lg ^ (lrow & 7)) * 8;

    f32x4 acc[8][2] = {};
    int slot = 0;
    for (int t = 0; t < NT; ++t) {
        if (t + 1 < NT) asm volatile("s_waitcnt vmcnt(6)" ::: "memory");
        else            asm volatile("s_waitcnt vmcnt(0)" ::: "memory");
        __builtin_amdgcn_s_barrier();
        __builtin_amdgcn_sched_barrier(0);
        if (t + 2 < NT) stage(slot == 0 ? 2 : slot - 1);

        const u16* sb = dyn + slot * 24576;
        short8 af[4][2], bf[2][2];
#pragma unroll
        for (int m = 0; m < 4; ++m) {
            af[m][0] = *(const short8*)(sb + rowAb + m * 1024 + cOff);
            af[m][1] = *(const short8*)(sb + rowAb + m * 1024 + (cOff ^ 32));
        }
#pragma unroll
        for (int n = 0; n < 2; ++n) {
            bf[n][0] = *(const short8*)(sb + rowBb + n * 1024 + cOff);
            bf[n][1] = *(const short8*)(sb + rowBb + n * 1024 + (cOff ^ 32));
        }
        __builtin_amdgcn_s_setprio(1);
#pragma unroll
        for (int m = 0; m < 4; ++m)
#pragma unroll
            for (int n = 0; n < 2; ++n) {
                acc[m][n] = __builtin_amdgcn_mfma_f32_16x16x32_bf16(af[m][0], bf[n][0], acc[m][n], 0, 0, 0);
                acc[m][n] = __builtin_amdgcn_mfma_f32_16x16x32_bf16(af[m][1], bf[n][1], acc[m][n], 0, 0, 0);
            }
        __builtin_amdgcn_s_setprio(0);
#pragma unroll
        for (int m = 0; m < 4; ++m) {
            af[m][0] = *(const short8*)(sb + rowAb + (m + 4) * 1024 + cOff);
            af[m][1] = *(const short8*)(sb + rowAb + (m + 4) * 1024 + (cOff ^ 32));
        }
        __builtin_amdgcn_s_setprio(1);
#pragma unroll
        for (int m = 0; m < 4; ++m)
#pragma unroll
            for (int n = 0; n < 2; ++n) {
                acc[m + 4][n] = __builtin_amdgcn_mfma_f32_16x16x32_bf16(af[m][0], bf[n][0], acc[m + 4][n], 0, 0, 0);
                acc[m + 4][n] = __builtin_amdgcn_mfma_f32_16x16x32_bf16(af[m][1], bf[n][1], acc[m + 4][n], 0, 0, 0);
            }
        __builtin_amdgcn_s_setprio(0);
        slot = slot == 2 ? 0 : slot + 1;
    }

#pragma unroll
    for (int m = 0; m < 8; ++m)
#pragma unroll
        for (int n = 0; n < 2; ++n)
#pragma unroll
            for (int j = 0; j < 4; ++j) {
                int gm = m0 + wm * 128 + m * 16 + 4 * lg + j;
                int gn = n0 + wn * 32 + n * 16 + lrow;
                float v = acc[m][n][j];
                if (RESID) v += resid[(size_t)gm * ldc + gn];
                if (OUT_BF16) ((u16*)C)[(size_t)gm * ldc + gn] = f2bf(v);
                else ((float*)C)[(size_t)gm * ldc + gn] = v;
            }
}

// ---- gate/up GEMM + SiLU on the gemm256 schedule: 256x64-per-matrix tile ----
// Same race-free 3-slot/vmcnt(6) structure; per slot: A 256x64 (16384 u16) +
// G 64x64 (4096) + U 64x64 (4096) = 48KB; 6 gll16/thread/tile (same vmcnt math).
__global__ __launch_bounds__(512, 2) void gemm_gu256(
    const u16* __restrict__ A, const u16* __restrict__ Bg, const u16* __restrict__ Bu,
    u16* __restrict__ C, int ldc, int K, int nx) {
    extern __shared__ u16 dyn[];
    const int tid = threadIdx.x;
    const int lane = tid & 63, wid = tid >> 6;
    const int lrow = lane & 15, lg = lane >> 4;
    const int wm = wid >> 2, wn = wid & 3;

    const int orig = blockIdx.x;
    const int wg = (orig & 7) * ((int)gridDim.x >> 3) + (orig >> 3);
    const int m0 = (wg / nx) * 256, n0 = (wg % nx) * 64;

    const u16* ga[4]; const u16* gg; const u16* gu;
    int lA[4];
#pragma unroll
    for (int i = 0; i < 4; ++i) {
        int c = tid + 512 * i, r = c >> 3, kc = (c & 7) ^ (r & 7);
        ga[i] = A + (size_t)(m0 + r) * K + kc * 8;
        lA[i] = c * 8;
    }
    {
        int c = tid, r = c >> 3, kc = (c & 7) ^ (r & 7);
        gg = Bg + (size_t)(n0 + r) * K + kc * 8;
        gu = Bu + (size_t)(n0 + r) * K + kc * 8;
    }
    const int lG = 16384 + tid * 8, lU = 20480 + tid * 8;
    const int NT = K >> 6;

    auto stage = [&](int slot) {
        u16* s = dyn + slot * 24576;
#pragma unroll
        for (int i = 0; i < 4; ++i) { gll16(ga[i], s + lA[i]); ga[i] += 64; }
        gll16(gg, s + lG); gg += 64;
        gll16(gu, s + lU); gu += 64;
    };

    stage(0);
    stage(1);

    const int rowAb = (wm * 128 + lrow) * 64;
    const int rowGb = 16384 + (wn * 16 + lrow) * 64;
    const int rowUb = 20480 + (wn * 16 + lrow) * 64;
    const int cOff = (lg ^ (lrow & 7)) * 8;

    f32x4 accg[8] = {};
    f32x4 accu[8] = {};
    int slot = 0;
    for (int t = 0; t < NT; ++t) {
        if (t + 1 < NT) asm volatile("s_waitcnt vmcnt(6)" ::: "memory");
        else            asm volatile("s_waitcnt vmcnt(0)" ::: "memory");
        __builtin_amdgcn_s_barrier();
        __builtin_amdgcn_sched_barrier(0);
        if (t + 2 < NT) stage(slot == 0 ? 2 : slot - 1);

        const u16* sb = dyn + slot * 24576;
        short8 af[4][2], gf[2], uf[2];
        gf[0] = *(const short8*)(sb + rowGb + cOff);
        gf[1] = *(const short8*)(sb + rowGb + (cOff ^ 32));
        uf[0] = *(const short8*)(sb + rowUb + cOff);
        uf[1] = *(const short8*)(sb + rowUb + (cOff ^ 32));
#pragma unroll
        for (int m = 0; m < 4; ++m) {
            af[m][0] = *(const short8*)(sb + rowAb + m * 1024 + cOff);
            af[m][1] = *(const short8*)(sb + rowAb + m * 1024 + (cOff ^ 32));
        }
        __builtin_amdgcn_s_setprio(1);
#pragma unroll
        for (int m = 0; m < 4; ++m) {
            accg[m] = __builtin_amdgcn_mfma_f32_16x16x32_bf16(af[m][0], gf[0], accg[m], 0, 0, 0);
            accg[m] = __builtin_amdgcn_mfma_f32_16x16x32_bf16(af[m][1], gf[1], accg[m], 0, 0, 0);
            accu[m] = __builtin_amdgcn_mfma_f32_16x16x32_bf16(af[m][0], uf[0], accu[m], 0, 0, 0);
            accu[m] = __builtin_amdgcn_mfma_f32_16x16x32_bf16(af[m][1], uf[1], accu[m], 0, 0, 0);
        }
        __builtin_amdgcn_s_setprio(0);
#pragma unroll
        for (int m = 0; m < 4; ++m) {
            af[m][0] = *(const short8*)(sb + rowAb + (m + 4) * 1024 + cOff);
            af[m][1] = *(const short8*)(sb + rowAb + (m + 4) * 1024 + (cOff ^ 32));
        }
        __builtin_amdgcn_s_setprio(1);
#pragma unroll
        for (int m = 0; m < 4; ++m) {
            accg[m + 4] = __builtin_amdgcn_mfma_f32_16x16x32_bf16(af[m][0], gf[0], accg[m + 4], 0, 0, 0);
            accg[m + 4] = __builtin_amdgcn_mfma_f32_16x16x32_bf16(af[m][1], gf[1], accg[m + 4], 0, 0, 0);
            accu[m + 4] = __builtin_amdgcn_mfma_f32_16x16x32_bf16(af[m][0], uf[0], accu[m + 4], 0, 0, 0);
            accu[m + 4] = __builtin_amdgcn_mfma_f32_16x16x32_bf16(af[m][1], uf[1], accu[m + 4], 0, 0, 0);
        }
        __builtin_amdgcn_s_setprio(0);
        slot = slot == 2 ? 0 : slot + 1;
    }

#pragma unroll
    for (int m = 0; m < 8; ++m)
#pragma unroll
        for (int j = 0; j < 4; ++j) {
            int gm = m0 + wm * 128 + m * 16 + 4 * lg + j;
            int gn = n0 + wn * 16 + lrow;
            float g = accg[m][j];
            float u = accu[m][j];
            float v = g / (1.f + __expf(-g)) * u;
            C[(size_t)gm * ldc + gn] = f2bf(v);
        }
}

// ---------------- flash attention (causal), 64-row Q tiles, 4 waves ----------------
// DS-diet: V staged as k-quad b64 writes (8/thread, was 32 b16); softmax
// reductions on VALU DPP (was 32 ds_swizzle); Q pre-scaled in RoPE.

__global__ __launch_bounds__(256) void attn_kernel(
    const u16* __restrict__ Q, const u16* __restrict__ K, const u16* __restrict__ V,
    u16* __restrict__ O, int vstride) {
    const int bh = blockIdx.y;
    const int b = bh >> 4, h = bh & 15;
    const int q0 = ((int)gridDim.x - 1 - (int)blockIdx.x) * 64;   // heavy-first
    const int tid = threadIdx.x, wid = tid >> 6, lane = tid & 63;
    const int lrow = lane & 15, lg = lane >> 4;

    __shared__ u16 Ks[64 * 128];     // byte = r*256 + 2d ^ ((r&7)<<4)
    __shared__ u16 Vt[128 * 64];     // byte = d*128 + 2k ^ ((d&7)<<4)
    __shared__ u16 Ps[4][16 * 64];   // per-wave P

    const int qrow = q0 + wid * 16;
    short8 qf[4];
    {
        const u16* Qb = Q + ((size_t)(b * SS + qrow + lrow)) * HID + h * HD;
#pragma unroll
        for (int kc = 0; kc < 4; ++kc) qf[kc] = *(const short8*)(Qb + kc * 32 + lg * 8);
    }

    // K staging: row kr+16i, cols kdc..+7.  V staging: k-quad 4*r4..+3, d cols vdc..+7
    const int kr = tid >> 4, kdc = (tid & 15) * 8;
    const int r4 = tid & 15, vdc = (tid >> 4) * 8;
    const u16* Kp = K + ((size_t)(b * SS + kr)) * HID + h * HD + kdc;
    const u16* Vp = V + ((size_t)(b * SS + 4 * r4)) * vstride + h * HD + vdc;

    short8 kpre[4], vpre[4];
#pragma unroll
    for (int i = 0; i < 4; ++i) kpre[i] = *(const short8*)(Kp + (size_t)(16 * i) * HID);
#pragma unroll
    for (int i = 0; i < 4; ++i) vpre[i] = *(const short8*)(Vp + (size_t)i * vstride);

    f32x4 oacc[8] = {};
    float mrun[4] = {-3e38f, -3e38f, -3e38f, -3e38f};
    float lrun[4] = {0.f, 0.f, 0.f, 0.f};

    for (int j0 = 0; j0 <= q0; j0 += 64) {
        __syncthreads();
#pragma unroll
        for (int i = 0; i < 4; ++i) {            // K: 4x b128 swizzled
            int r = kr + 16 * i;
            *(short8*)((char*)Ks + ((r * 256 + kdc * 2) ^ ((r & 7) << 4))) = kpre[i];
        }
#pragma unroll
        for (int d = 0; d < 8; ++d) {            // V: 8x b64 (k-quad pack)
            short4v p = {vpre[0][d], vpre[1][d], vpre[2][d], vpre[3][d]};
            *(short4v*)((char*)Vt + ((((vdc + d) * 128) + 8 * r4) ^ (d << 4))) = p;
        }
        __syncthreads();

        f32x4 sacc[4] = {};
        __builtin_amdgcn_s_setprio(1);
#pragma unroll
        for (int n = 0; n < 4; ++n) {
#pragma unroll
            for (int kc = 0; kc < 4; ++kc) {
                int r = n * 16 + lrow;
                short8 kf = *(const short8*)((const char*)Ks +
                            ((r * 256 + (kc * 32 + lg * 8) * 2) ^ ((r & 7) << 4)));
                sacc[n] = __builtin_amdgcn_mfma_f32_16x16x32_bf16(qf[kc], kf, sacc[n], 0, 0, 0);
            }
        }
        __builtin_amdgcn_s_setprio(0);

        const bool diag = (j0 == q0);
        float pm[4] = {-3e38f, -3e38f, -3e38f, -3e38f};
#pragma unroll
        for (int n = 0; n < 4; ++n)
#pragma unroll
            for (int j = 0; j < 4; ++j) {
                float sv = sacc[n][j];
                if (diag && (n * 16 + lrow > wid * 16 + 4 * lg + j)) sv = -1e30f;
                sacc[n][j] = sv;
                pm[j] = fmaxf(pm[j], sv);
            }

        // prefetch next K/V tile (latency hides under softmax+PV)
        if (j0 < q0) {
            const u16* Kn = Kp + (size_t)(j0 + 64) * HID;
            const u16* Vn = Vp + (size_t)(j0 + 64) * vstride;
#pragma unroll
            for (int i = 0; i < 4; ++i) kpre[i] = *(const short8*)(Kn + (size_t)(16 * i) * HID);
#pragma unroll
            for (int i = 0; i < 4; ++i) vpre[i] = *(const short8*)(Vn + (size_t)i * vstride);
        }

#pragma unroll
        for (int j = 0; j < 4; ++j) pm[j] = rmax16(pm[j]);

        float sf[4], rs[4];
#pragma unroll
        for (int j = 0; j < 4; ++j) {
            float mnew = fmaxf(mrun[j], pm[j]);
            sf[j] = __expf(mrun[j] - mnew);
            mrun[j] = mnew;
            rs[j] = 0.f;
        }
#pragma unroll
        for (int n = 0; n < 4; ++n)
#pragma unroll
            for (int j = 0; j < 4; ++j) {
                float p = __expf(sacc[n][j] - mrun[j]);
                sacc[n][j] = p;
                rs[j] += p;
            }
#pragma unroll
        for (int j = 0; j < 4; ++j) {
            rs[j] = rsum16(rs[j]);
            lrun[j] = lrun[j] * sf[j] + rs[j];
        }
#pragma unroll
        for (int n = 0; n < 8; ++n)
#pragma unroll
            for (int j = 0; j < 4; ++j) oacc[n][j] *= sf[j];

#pragma unroll
        for (int n = 0; n < 4; ++n)
#pragma unroll
            for (int j = 0; j < 4; ++j) {
                int row = 4 * lg + j, col = n * 16 + lrow;
                *(u16*)((char*)&Ps[wid][0] + ((row * 128 + col * 2) ^ ((row & 7) << 4))) =
                    f2bf(sacc[n][j]);
            }
        short8 pf[2];
#pragma unroll
        for (int ks = 0; ks < 2; ++ks)
            pf[ks] = *(const short8*)((const char*)&Ps[wid][0] +
                     ((lrow * 128 + (ks * 32 + lg * 8) * 2) ^ ((lrow & 7) << 4)));
        __builtin_amdgcn_s_setprio(1);
#pragma unroll
        for (int n = 0; n < 8; ++n) {
            int d = n * 16 + lrow;
#pragma unroll
            for (int ks = 0; ks < 2; ++ks) {
                short8 vf = *(const short8*)((const char*)Vt +
                            ((d * 128 + (ks * 32 + lg * 8) * 2) ^ ((d & 7) << 4)));
                oacc[n] = __builtin_amdgcn_mfma_f32_16x16x32_bf16(pf[ks], vf, oacc[n], 0, 0, 0);
            }
        }
        __builtin_amdgcn_s_setprio(0);
    }

#pragma unroll
    for (int n = 0; n < 8; ++n)
#pragma unroll
        for (int j = 0; j < 4; ++j) {
            int row = qrow + 4 * lg + j;
            O[((size_t)(b * SS + row)) * HID + h * HD + n * 16 + lrow] =
                f2bf(oacc[n][j] / lrun[j]);
        }
}

// ---------------- launcher ----------------

extern "C" void kernel_launch(void* const* d_in, const int* in_sizes, int n_in,
                              void* d_out, int out_size, void* d_ws, size_t ws_size,
                              hipStream_t stream) {
    const float* x    = (const float*)d_in[0];
    const float* ln1w = (const float*)d_in[1];
    const float* ln1b = (const float*)d_in[2];
    const float* ln2w = (const float*)d_in[3];
    const float* ln2b = (const float*)d_in[4];
    const float* wq   = (const float*)d_in[5];
    const float* wk   = (const float*)d_in[6];
    const float* wv   = (const float*)d_in[7];
    const float* wo   = (const float*)d_in[8];
    const float* wg   = (const float*)d_in[9];
    const float* wu   = (const float*)d_in[10];
    const float* wd   = (const float*)d_in[11];

    char* ws = (char*)d_ws;
    u16*    Wbuf = (u16*)(ws);                       // 32 MiB, reused per-GEMM
    u16*    hb   = (u16*)(ws + (32UL << 20));        // 16 MiB  LN out (bf16)
    u16*    qkvb = (u16*)(ws + (48UL << 20));        // 48 MiB  QKV bf16 [4096][6144]
    u16*    qb   = (u16*)(ws + (96UL << 20));        // 16 MiB
    u16*    kb   = (u16*)(ws + (112UL << 20));       // 16 MiB
    u16*    ob   = (u16*)(ws + (128UL << 20));       // 16 MiB
    float*  x2   = (float*)(ws + (144UL << 20));     // 32 MiB  fp32 residual stream
    float2* cs   = (float2*)(ws + (176UL << 20));    // 1 MiB   rope cos/sin
    u16*    mb   = qkvb;                             // 64 MiB alias

    trig_kernel<<<512, 256, 0, stream>>>(cs);
    ln_kernel<<<4096, 256, 0, stream>>>(x, ln1w, ln1b, hb);

    // QKV projection
    cast_f32_bf16_kernel<<<2048, 256, 0, stream>>>(wq, Wbuf, 524288);
    cast_f32_bf16_kernel<<<2048, 256, 0, stream>>>(wk, Wbuf + 4194304, 524288);
    cast_f32_bf16_kernel<<<2048, 256, 0, stream>>>(wv, Wbuf + 8388608, 524288);
    gemm256<1, 0><<<768, 512, 147456, stream>>>(hb, Wbuf, qkvb, nullptr, 6144, 2048, 48);

    rope_kernel<<<16384, 256, 0, stream>>>(qkvb, qb, cs, 0.08838834764831845f);
    rope_kernel<<<16384, 256, 0, stream>>>(qkvb + 2048, kb, cs, 1.0f);
    attn_kernel<<<dim3(32, 32), 256, 0, stream>>>(qb, kb, qkvb + 4096, ob, 6144);

    // O projection + residual (fp32 out)
    cast_f32_bf16_kernel<<<2048, 256, 0, stream>>>(wo, Wbuf, 524288);
    gemm256<0, 1><<<256, 512, 147456, stream>>>(ob, Wbuf, x2, x, 2048, 2048, 16);

    ln_kernel<<<4096, 256, 0, stream>>>(x2, ln2w, ln2b, hb);

    // MLP gate/up in two 4096-column halves (SiLU fused in epilogue)
    for (int h = 0; h < 2; ++h) {
        cast_f32_bf16_kernel<<<4096, 256, 0, stream>>>(wg + (size_t)h * 8388608, Wbuf, 1048576);
        cast_f32_bf16_kernel<<<4096, 256, 0, stream>>>(wu + (size_t)h * 8388608, Wbuf + 8388608, 1048576);
        gemm_gu256<<<1024, 512, 147456, stream>>>(hb, Wbuf, Wbuf + 8388608,
                                                  mb + h * 4096, 8192, 2048, 64);
    }

    // Down projection + residual -> fp32 d_out
    cast_f32_bf16_kernel<<<8192, 256, 0, stream>>>(wd, Wbuf, 2097152);
    gemm256<0, 1><<<256, 512, 147456, stream>>>(mb, Wbuf, (float*)d_out, x2, 2048, 8192, 16);
}

// Round 8
// 789.143 us; speedup vs baseline: 1.7278x; 1.0784x over previous
//
#include <hip/hip_runtime.h>
#include <hip/hip_bf16.h>

#define HID 2048
#define NH 16
#define HD 128
#define INTER 8192
#define SS 2048

typedef unsigned short u16;
typedef __attribute__((ext_vector_type(8))) short short8;
typedef __attribute__((ext_vector_type(4))) short short4v;
typedef __attribute__((ext_vector_type(4))) float f32x4;

__device__ __forceinline__ float bf2f(u16 u) {
    unsigned v = ((unsigned)u) << 16; float f; __builtin_memcpy(&f, &v, 4); return f;
}
__device__ __forceinline__ u16 f2bf(float f) {
    unsigned u; __builtin_memcpy(&u, &f, 4);
    u = u + 0x7FFFu + ((u >> 16) & 1u);   // RNE
    return (u16)(u >> 16);
}

typedef const __attribute__((address_space(1))) void* gas_t;
typedef __attribute__((address_space(3))) void* las_t;
__device__ __forceinline__ void gll16(const void* g, void* l) {
    __builtin_amdgcn_global_load_lds((gas_t)g, (las_t)l, 16, 0, 0);
}

// VALU-pipe cross-lane via DPP (16-lane-row butterfly).
template <int CTRL>
__device__ __forceinline__ float dppf(float x) {
    union { float f; int i; } u; u.f = x;
    u.i = __builtin_amdgcn_update_dpp(u.i, u.i, CTRL, 0xf, 0xf, false);
    return u.f;
}
__device__ __forceinline__ float rmax16(float x) {
    x = fmaxf(x, dppf<0xB1>(x));
    x = fmaxf(x, dppf<0x4E>(x));
    x = fmaxf(x, dppf<0x141>(x));
    x = fmaxf(x, dppf<0x140>(x));
    return x;
}
__device__ __forceinline__ float rsum16(float x) {
    x = x + dppf<0xB1>(x);
    x = x + dppf<0x4E>(x);
    x = x + dppf<0x141>(x);
    x = x + dppf<0x140>(x);
    return x;
}

// ---------------- elementwise / prep kernels ----------------

__global__ __launch_bounds__(256) void cast_f32_bf16_kernel(
    const float* __restrict__ src, u16* __restrict__ dst, int n8) {
    int gid = blockIdx.x * 256 + threadIdx.x;
    if (gid >= n8) return;
    const float4* s = (const float4*)src + (size_t)gid * 2;
    float4 a = s[0], b = s[1];
    short8 o;
    o[0] = (short)f2bf(a.x); o[1] = (short)f2bf(a.y); o[2] = (short)f2bf(a.z); o[3] = (short)f2bf(a.w);
    o[4] = (short)f2bf(b.x); o[5] = (short)f2bf(b.y); o[6] = (short)f2bf(b.z); o[7] = (short)f2bf(b.w);
    *((short8*)dst + gid) = o;
}

__global__ __launch_bounds__(256) void trig_kernel(float2* __restrict__ cs) {
    int id = blockIdx.x * 256 + threadIdx.x;   // < 2048*64
    int s = id >> 6, d = id & 63;
    float freq = expf(-(float)(2 * d) * (1.0f / (float)HD) * 9.210340371976184f); // ln(10000)
    float ang = (float)s * freq;
    cs[id] = make_float2(cosf(ang), sinf(ang));
}

__global__ __launch_bounds__(256) void ln_kernel(
    const float* __restrict__ X, const float* __restrict__ W, const float* __restrict__ Bv,
    u16* __restrict__ out) {
    const int row = blockIdx.x, tid = threadIdx.x;
    const float* xr = X + (size_t)row * HID;
    float4 v0 = ((const float4*)xr)[tid * 2];
    float4 v1 = ((const float4*)xr)[tid * 2 + 1];
    float e[8] = {v0.x, v0.y, v0.z, v0.w, v1.x, v1.y, v1.z, v1.w};
    float s = 0.f, ss2 = 0.f;
#pragma unroll
    for (int i = 0; i < 8; ++i) { s += e[i]; ss2 += e[i] * e[i]; }
#pragma unroll
    for (int m = 1; m < 64; m <<= 1) { s += __shfl_xor(s, m, 64); ss2 += __shfl_xor(ss2, m, 64); }
    __shared__ float red[8];
    if ((tid & 63) == 0) { red[tid >> 6] = s; red[4 + (tid >> 6)] = ss2; }
    __syncthreads();
    s = red[0] + red[1] + red[2] + red[3];
    ss2 = red[4] + red[5] + red[6] + red[7];
    float mean = s * (1.0f / HID);
    float var = ss2 * (1.0f / HID) - mean * mean;
    float rstd = rsqrtf(var + 1e-5f);
    float4 w0 = ((const float4*)W)[tid * 2], w1 = ((const float4*)W)[tid * 2 + 1];
    float4 b0 = ((const float4*)Bv)[tid * 2], b1 = ((const float4*)Bv)[tid * 2 + 1];
    float wv[8] = {w0.x, w0.y, w0.z, w0.w, w1.x, w1.y, w1.z, w1.w};
    float bv[8] = {b0.x, b0.y, b0.z, b0.w, b1.x, b1.y, b1.z, b1.w};
    short8 o;
#pragma unroll
    for (int i = 0; i < 8; ++i) o[i] = (short)f2bf((e[i] - mean) * rstd * wv[i] + bv[i]);
    *((short8*)(out + (size_t)row * HID) + tid) = o;
}

// RoPE on bf16 input (row stride 6144) with output pre-scale (Q gets log2e/sqrt(D))
__global__ __launch_bounds__(256) void rope_kernel(
    const u16* __restrict__ src, u16* __restrict__ dst, const float2* __restrict__ cs,
    float oscale) {
    int gid = blockIdx.x * 256 + threadIdx.x;   // < 4096*16*64
    int d = gid & 63;
    int rh = gid >> 6;
    int h = rh & (NH - 1);
    int row = rh >> 4;               // b*2048+s
    int s = row & (SS - 1);
    unsigned pair = *(const unsigned*)(src + (size_t)row * 6144 + h * HD + 2 * d);
    float x1 = bf2f((u16)(pair & 0xFFFFu));
    float x2 = bf2f((u16)(pair >> 16));
    float2 t = cs[s * 64 + d];
    u16* q = dst + (size_t)row * HID + h * HD;
    q[d] = f2bf((x1 * t.x - x2 * t.y) * oscale);
    q[64 + d] = f2bf((x1 * t.y + x2 * t.x) * oscale);
}

// ---------------- GEMM 256x128 phase-scheduled (T1+T2+T4+T5) ----------------
template <int OUT_BF16, int RESID>
__global__ __launch_bounds__(512, 2) void gemm256(
    const u16* __restrict__ A, const u16* __restrict__ B,
    void* __restrict__ C, const float* __restrict__ resid,
    int ldc, int K, int nx) {
    extern __shared__ u16 dyn[];    // 3 slots x (A 256x64 + B 128x64) u16
    const int tid = threadIdx.x;
    const int lane = tid & 63, wid = tid >> 6;
    const int lrow = lane & 15, lg = lane >> 4;
    const int wm = wid >> 2, wn = wid & 3;

    const int orig = blockIdx.x;
    const int wg = (orig & 7) * ((int)gridDim.x >> 3) + (orig >> 3);
    const int bx = wg % nx, by = wg / nx;
    const int m0 = by * 256, n0 = bx * 128;

    const u16* ga[4]; const u16* gb[2];
    int lA[4], lB[2];
#pragma unroll
    for (int i = 0; i < 4; ++i) {
        int c = tid + 512 * i, r = c >> 3, kc = (c & 7) ^ (r & 7);
        ga[i] = A + (size_t)(m0 + r) * K + kc * 8;
        lA[i] = c * 8;
    }
#pragma unroll
    for (int i = 0; i < 2; ++i) {
        int c = tid + 512 * i, r = c >> 3, kc = (c & 7) ^ (r & 7);
        gb[i] = B + (size_t)(n0 + r) * K + kc * 8;
        lB[i] = 16384 + c * 8;
    }
    const int NT = K >> 6;

    auto stage = [&](int slot) {
        u16* s = dyn + slot * 24576;
#pragma unroll
        for (int i = 0; i < 4; ++i) { gll16(ga[i], s + lA[i]); ga[i] += 64; }
#pragma unroll
        for (int i = 0; i < 2; ++i) { gll16(gb[i], s + lB[i]); gb[i] += 64; }
    };

    stage(0);
    stage(1);

    const int rowAb = (wm * 128 + lrow) * 64;
    const int rowBb = 16384 + (wn * 32 + lrow) * 64;
    const int cOff = (lg ^ (lrow & 7)) * 8;

    f32x4 acc[8][2] = {};
    int slot = 0;
    for (int t = 0; t < NT; ++t) {
        if (t + 1 < NT) asm volatile("s_waitcnt vmcnt(6)" ::: "memory");
        else            asm volatile("s_waitcnt vmcnt(0)" ::: "memory");
        __builtin_amdgcn_s_barrier();
        __builtin_amdgcn_sched_barrier(0);
        if (t + 2 < NT) stage(slot == 0 ? 2 : slot - 1);

        const u16* sb = dyn + slot * 24576;
        short8 af[4][2], bf[2][2];
#pragma unroll
        for (int m = 0; m < 4; ++m) {
            af[m][0] = *(const short8*)(sb + rowAb + m * 1024 + cOff);
            af[m][1] = *(const short8*)(sb + rowAb + m * 1024 + (cOff ^ 32));
        }
#pragma unroll
        for (int n = 0; n < 2; ++n) {
            bf[n][0] = *(const short8*)(sb + rowBb + n * 1024 + cOff);
            bf[n][1] = *(const short8*)(sb + rowBb + n * 1024 + (cOff ^ 32));
        }
        __builtin_amdgcn_s_setprio(1);
#pragma unroll
        for (int m = 0; m < 4; ++m)
#pragma unroll
            for (int n = 0; n < 2; ++n) {
                acc[m][n] = __builtin_amdgcn_mfma_f32_16x16x32_bf16(af[m][0], bf[n][0], acc[m][n], 0, 0, 0);
                acc[m][n] = __builtin_amdgcn_mfma_f32_16x16x32_bf16(af[m][1], bf[n][1], acc[m][n], 0, 0, 0);
            }
        __builtin_amdgcn_s_setprio(0);
#pragma unroll
        for (int m = 0; m < 4; ++m) {
            af[m][0] = *(const short8*)(sb + rowAb + (m + 4) * 1024 + cOff);
            af[m][1] = *(const short8*)(sb + rowAb + (m + 4) * 1024 + (cOff ^ 32));
        }
        __builtin_amdgcn_s_setprio(1);
#pragma unroll
        for (int m = 0; m < 4; ++m)
#pragma unroll
            for (int n = 0; n < 2; ++n) {
                acc[m + 4][n] = __builtin_amdgcn_mfma_f32_16x16x32_bf16(af[m][0], bf[n][0], acc[m + 4][n], 0, 0, 0);
                acc[m + 4][n] = __builtin_amdgcn_mfma_f32_16x16x32_bf16(af[m][1], bf[n][1], acc[m + 4][n], 0, 0, 0);
            }
        __builtin_amdgcn_s_setprio(0);
        slot = slot == 2 ? 0 : slot + 1;
    }

#pragma unroll
    for (int m = 0; m < 8; ++m)
#pragma unroll
        for (int n = 0; n < 2; ++n)
#pragma unroll
            for (int j = 0; j < 4; ++j) {
                int gm = m0 + wm * 128 + m * 16 + 4 * lg + j;
                int gn = n0 + wn * 32 + n * 16 + lrow;
                float v = acc[m][n][j];
                if (RESID) v += resid[(size_t)gm * ldc + gn];
                if (OUT_BF16) ((u16*)C)[(size_t)gm * ldc + gn] = f2bf(v);
                else ((float*)C)[(size_t)gm * ldc + gn] = v;
            }
}

// ---- gate/up GEMM + SiLU on the gemm256 schedule: 256x64-per-matrix tile ----
__global__ __launch_bounds__(512, 2) void gemm_gu256(
    const u16* __restrict__ A, const u16* __restrict__ Bg, const u16* __restrict__ Bu,
    u16* __restrict__ C, int ldc, int K, int nx) {
    extern __shared__ u16 dyn[];
    const int tid = threadIdx.x;
    const int lane = tid & 63, wid = tid >> 6;
    const int lrow = lane & 15, lg = lane >> 4;
    const int wm = wid >> 2, wn = wid & 3;

    const int orig = blockIdx.x;
    const int wg = (orig & 7) * ((int)gridDim.x >> 3) + (orig >> 3);
    const int m0 = (wg / nx) * 256, n0 = (wg % nx) * 64;

    const u16* ga[4]; const u16* gg; const u16* gu;
    int lA[4];
#pragma unroll
    for (int i = 0; i < 4; ++i) {
        int c = tid + 512 * i, r = c >> 3, kc = (c & 7) ^ (r & 7);
        ga[i] = A + (size_t)(m0 + r) * K + kc * 8;
        lA[i] = c * 8;
    }
    {
        int c = tid, r = c >> 3, kc = (c & 7) ^ (r & 7);
        gg = Bg + (size_t)(n0 + r) * K + kc * 8;
        gu = Bu + (size_t)(n0 + r) * K + kc * 8;
    }
    const int lG = 16384 + tid * 8, lU = 20480 + tid * 8;
    const int NT = K >> 6;

    auto stage = [&](int slot) {
        u16* s = dyn + slot * 24576;
#pragma unroll
        for (int i = 0; i < 4; ++i) { gll16(ga[i], s + lA[i]); ga[i] += 64; }
        gll16(gg, s + lG); gg += 64;
        gll16(gu, s + lU); gu += 64;
    };

    stage(0);
    stage(1);

    const int rowAb = (wm * 128 + lrow) * 64;
    const int rowGb = 16384 + (wn * 16 + lrow) * 64;
    const int rowUb = 20480 + (wn * 16 + lrow) * 64;
    const int cOff = (lg ^ (lrow & 7)) * 8;

    f32x4 accg[8] = {};
    f32x4 accu[8] = {};
    int slot = 0;
    for (int t = 0; t < NT; ++t) {
        if (t + 1 < NT) asm volatile("s_waitcnt vmcnt(6)" ::: "memory");
        else            asm volatile("s_waitcnt vmcnt(0)" ::: "memory");
        __builtin_amdgcn_s_barrier();
        __builtin_amdgcn_sched_barrier(0);
        if (t + 2 < NT) stage(slot == 0 ? 2 : slot - 1);

        const u16* sb = dyn + slot * 24576;
        short8 af[4][2], gf[2], uf[2];
        gf[0] = *(const short8*)(sb + rowGb + cOff);
        gf[1] = *(const short8*)(sb + rowGb + (cOff ^ 32));
        uf[0] = *(const short8*)(sb + rowUb + cOff);
        uf[1] = *(const short8*)(sb + rowUb + (cOff ^ 32));
#pragma unroll
        for (int m = 0; m < 4; ++m) {
            af[m][0] = *(const short8*)(sb + rowAb + m * 1024 + cOff);
            af[m][1] = *(const short8*)(sb + rowAb + m * 1024 + (cOff ^ 32));
        }
        __builtin_amdgcn_s_setprio(1);
#pragma unroll
        for (int m = 0; m < 4; ++m) {
            accg[m] = __builtin_amdgcn_mfma_f32_16x16x32_bf16(af[m][0], gf[0], accg[m], 0, 0, 0);
            accg[m] = __builtin_amdgcn_mfma_f32_16x16x32_bf16(af[m][1], gf[1], accg[m], 0, 0, 0);
            accu[m] = __builtin_amdgcn_mfma_f32_16x16x32_bf16(af[m][0], uf[0], accu[m], 0, 0, 0);
            accu[m] = __builtin_amdgcn_mfma_f32_16x16x32_bf16(af[m][1], uf[1], accu[m], 0, 0, 0);
        }
        __builtin_amdgcn_s_setprio(0);
#pragma unroll
        for (int m = 0; m < 4; ++m) {
            af[m][0] = *(const short8*)(sb + rowAb + (m + 4) * 1024 + cOff);
            af[m][1] = *(const short8*)(sb + rowAb + (m + 4) * 1024 + (cOff ^ 32));
        }
        __builtin_amdgcn_s_setprio(1);
#pragma unroll
        for (int m = 0; m < 4; ++m) {
            accg[m + 4] = __builtin_amdgcn_mfma_f32_16x16x32_bf16(af[m][0], gf[0], accg[m + 4], 0, 0, 0);
            accg[m + 4] = __builtin_amdgcn_mfma_f32_16x16x32_bf16(af[m][1], gf[1], accg[m + 4], 0, 0, 0);
            accu[m + 4] = __builtin_amdgcn_mfma_f32_16x16x32_bf16(af[m][0], uf[0], accu[m + 4], 0, 0, 0);
            accu[m + 4] = __builtin_amdgcn_mfma_f32_16x16x32_bf16(af[m][1], uf[1], accu[m + 4], 0, 0, 0);
        }
        __builtin_amdgcn_s_setprio(0);
        slot = slot == 2 ? 0 : slot + 1;
    }

#pragma unroll
    for (int m = 0; m < 8; ++m)
#pragma unroll
        for (int j = 0; j < 4; ++j) {
            int gm = m0 + wm * 128 + m * 16 + 4 * lg + j;
            int gn = n0 + wn * 16 + lrow;
            float g = accg[m][j];
            float u = accu[m][j];
            float v = g / (1.f + __expf(-g)) * u;
            C[(size_t)gm * ldc + gn] = f2bf(v);
        }
}

// ---------------- flash attention (causal), 64-row Q tiles, 4 waves ----------------
// blockIdx.x = bh (fast dim), blockIdx.y = q-level heavy-first => heaviest 32
// blocks dispatch FIRST, light blocks backfill (kills the 1-block/CU tail).
// Softmax in base-2 units (log2e folded into Q scale): bare v_exp_f32, no muls.
// T13 defer-max: skip max-update/rescale when __all(pm <= mrun + 11.5).

__global__ __launch_bounds__(256) void attn_kernel(
    const u16* __restrict__ Q, const u16* __restrict__ K, const u16* __restrict__ V,
    u16* __restrict__ O, int vstride) {
    const int bh = blockIdx.x;
    const int b = bh >> 4, h = bh & 15;
    const int q0 = ((int)gridDim.y - 1 - (int)blockIdx.y) * 64;   // heavy-first
    const int tid = threadIdx.x, wid = tid >> 6, lane = tid & 63;
    const int lrow = lane & 15, lg = lane >> 4;

    __shared__ u16 Ks[64 * 128];     // byte = r*256 + 2d ^ ((r&7)<<4)
    __shared__ u16 Vt[128 * 64];     // byte = d*128 + 2k ^ ((d&7)<<4)
    __shared__ u16 Ps[4][16 * 64];   // per-wave P

    const int qrow = q0 + wid * 16;
    short8 qf[4];
    {
        const u16* Qb = Q + ((size_t)(b * SS + qrow + lrow)) * HID + h * HD;
#pragma unroll
        for (int kc = 0; kc < 4; ++kc) qf[kc] = *(const short8*)(Qb + kc * 32 + lg * 8);
    }

    const int kr = tid >> 4, kdc = (tid & 15) * 8;
    const int r4 = tid & 15, vdc = (tid >> 4) * 8;
    const u16* Kp = K + ((size_t)(b * SS + kr)) * HID + h * HD + kdc;
    const u16* Vp = V + ((size_t)(b * SS + 4 * r4)) * vstride + h * HD + vdc;

    short8 kpre[4], vpre[4];
#pragma unroll
    for (int i = 0; i < 4; ++i) kpre[i] = *(const short8*)(Kp + (size_t)(16 * i) * HID);
#pragma unroll
    for (int i = 0; i < 4; ++i) vpre[i] = *(const short8*)(Vp + (size_t)i * vstride);

    f32x4 oacc[8] = {};
    float mrun[4] = {-3e38f, -3e38f, -3e38f, -3e38f};
    float lrun[4] = {0.f, 0.f, 0.f, 0.f};

    for (int j0 = 0; j0 <= q0; j0 += 64) {
        __syncthreads();
#pragma unroll
        for (int i = 0; i < 4; ++i) {            // K: 4x b128 swizzled
            int r = kr + 16 * i;
            *(short8*)((char*)Ks + ((r * 256 + kdc * 2) ^ ((r & 7) << 4))) = kpre[i];
        }
#pragma unroll
        for (int d = 0; d < 8; ++d) {            // V: 8x b64 (k-quad pack)
            short4v p = {vpre[0][d], vpre[1][d], vpre[2][d], vpre[3][d]};
            *(short4v*)((char*)Vt + ((((vdc + d) * 128) + 8 * r4) ^ (d << 4))) = p;
        }
        __syncthreads();

        f32x4 sacc[4] = {};
        __builtin_amdgcn_s_setprio(1);
#pragma unroll
        for (int n = 0; n < 4; ++n) {
#pragma unroll
            for (int kc = 0; kc < 4; ++kc) {
                int r = n * 16 + lrow;
                short8 kf = *(const short8*)((const char*)Ks +
                            ((r * 256 + (kc * 32 + lg * 8) * 2) ^ ((r & 7) << 4)));
                sacc[n] = __builtin_amdgcn_mfma_f32_16x16x32_bf16(qf[kc], kf, sacc[n], 0, 0, 0);
            }
        }
        __builtin_amdgcn_s_setprio(0);

        const bool diag = (j0 == q0);
        float pm[4] = {-3e38f, -3e38f, -3e38f, -3e38f};
#pragma unroll
        for (int n = 0; n < 4; ++n)
#pragma unroll
            for (int j = 0; j < 4; ++j) {
                float sv = sacc[n][j];
                if (diag && (n * 16 + lrow > wid * 16 + 4 * lg + j)) sv = -1e30f;
                sacc[n][j] = sv;
                pm[j] = fmaxf(pm[j], sv);
            }

        // prefetch next K/V tile (latency hides under softmax+PV)
        if (j0 < q0) {
            const u16* Kn = Kp + (size_t)(j0 + 64) * HID;
            const u16* Vn = Vp + (size_t)(j0 + 64) * vstride;
#pragma unroll
            for (int i = 0; i < 4; ++i) kpre[i] = *(const short8*)(Kn + (size_t)(16 * i) * HID);
#pragma unroll
            for (int i = 0; i < 4; ++i) vpre[i] = *(const short8*)(Vn + (size_t)i * vstride);
        }

#pragma unroll
        for (int j = 0; j < 4; ++j) pm[j] = rmax16(pm[j]);

        // T13 defer-max: p bounded by 2^11.5 when deferred (f32 accum safe)
        bool ok = (pm[0] <= mrun[0] + 11.5f) && (pm[1] <= mrun[1] + 11.5f) &&
                  (pm[2] <= mrun[2] + 11.5f) && (pm[3] <= mrun[3] + 11.5f);
        if (!__all(ok)) {
            float sf[4];
#pragma unroll
            for (int j = 0; j < 4; ++j) {
                float mnew = fmaxf(mrun[j], pm[j]);
                sf[j] = exp2f(mrun[j] - mnew);
                mrun[j] = mnew;
                lrun[j] *= sf[j];
            }
#pragma unroll
            for (int n = 0; n < 8; ++n)
#pragma unroll
                for (int j = 0; j < 4; ++j) oacc[n][j] *= sf[j];
        }

        float rs[4] = {0.f, 0.f, 0.f, 0.f};
#pragma unroll
        for (int n = 0; n < 4; ++n)
#pragma unroll
            for (int j = 0; j < 4; ++j) {
                float p = exp2f(sacc[n][j] - mrun[j]);
                sacc[n][j] = p;
                rs[j] += p;
            }
#pragma unroll
        for (int j = 0; j < 4; ++j) lrun[j] += rsum16(rs[j]);

#pragma unroll
        for (int n = 0; n < 4; ++n)
#pragma unroll
            for (int j = 0; j < 4; ++j) {
                int row = 4 * lg + j, col = n * 16 + lrow;
                *(u16*)((char*)&Ps[wid][0] + ((row * 128 + col * 2) ^ ((row & 7) << 4))) =
                    f2bf(sacc[n][j]);
            }
        short8 pf[2];
#pragma unroll
        for (int ks = 0; ks < 2; ++ks)
            pf[ks] = *(const short8*)((const char*)&Ps[wid][0] +
                     ((lrow * 128 + (ks * 32 + lg * 8) * 2) ^ ((lrow & 7) << 4)));
        __builtin_amdgcn_s_setprio(1);
#pragma unroll
        for (int n = 0; n < 8; ++n) {
            int d = n * 16 + lrow;
#pragma unroll
            for (int ks = 0; ks < 2; ++ks) {
                short8 vf = *(const short8*)((const char*)Vt +
                            ((d * 128 + (ks * 32 + lg * 8) * 2) ^ ((d & 7) << 4)));
                oacc[n] = __builtin_amdgcn_mfma_f32_16x16x32_bf16(pf[ks], vf, oacc[n], 0, 0, 0);
            }
        }
        __builtin_amdgcn_s_setprio(0);
    }

#pragma unroll
    for (int n = 0; n < 8; ++n)
#pragma unroll
        for (int j = 0; j < 4; ++j) {
            int row = qrow + 4 * lg + j;
            O[((size_t)(b * SS + row)) * HID + h * HD + n * 16 + lrow] =
                f2bf(oacc[n][j] / lrun[j]);
        }
}

// ---------------- launcher ----------------

extern "C" void kernel_launch(void* const* d_in, const int* in_sizes, int n_in,
                              void* d_out, int out_size, void* d_ws, size_t ws_size,
                              hipStream_t stream) {
    const float* x    = (const float*)d_in[0];
    const float* ln1w = (const float*)d_in[1];
    const float* ln1b = (const float*)d_in[2];
    const float* ln2w = (const float*)d_in[3];
    const float* ln2b = (const float*)d_in[4];
    const float* wq   = (const float*)d_in[5];
    const float* wk   = (const float*)d_in[6];
    const float* wv   = (const float*)d_in[7];
    const float* wo   = (const float*)d_in[8];
    const float* wg   = (const float*)d_in[9];
    const float* wu   = (const float*)d_in[10];
    const float* wd   = (const float*)d_in[11];

    char* ws = (char*)d_ws;
    u16*    Wbuf = (u16*)(ws);                       // 32 MiB, reused per-GEMM
    u16*    hb   = (u16*)(ws + (32UL << 20));        // 16 MiB  LN out (bf16)
    u16*    qkvb = (u16*)(ws + (48UL << 20));        // 48 MiB  QKV bf16 [4096][6144]
    u16*    qb   = (u16*)(ws + (96UL << 20));        // 16 MiB
    u16*    kb   = (u16*)(ws + (112UL << 20));       // 16 MiB
    u16*    ob   = (u16*)(ws + (128UL << 20));       // 16 MiB
    float*  x2   = (float*)(ws + (144UL << 20));     // 32 MiB  fp32 residual stream
    float2* cs   = (float2*)(ws + (176UL << 20));    // 1 MiB   rope cos/sin
    u16*    mb   = qkvb;                             // 64 MiB alias

    trig_kernel<<<512, 256, 0, stream>>>(cs);
    ln_kernel<<<4096, 256, 0, stream>>>(x, ln1w, ln1b, hb);

    // QKV projection
    cast_f32_bf16_kernel<<<2048, 256, 0, stream>>>(wq, Wbuf, 524288);
    cast_f32_bf16_kernel<<<2048, 256, 0, stream>>>(wk, Wbuf + 4194304, 524288);
    cast_f32_bf16_kernel<<<2048, 256, 0, stream>>>(wv, Wbuf + 8388608, 524288);
    gemm256<1, 0><<<768, 512, 147456, stream>>>(hb, Wbuf, qkvb, nullptr, 6144, 2048, 48);

    // Q scale = log2(e)/sqrt(128) so softmax runs in base-2 units
    rope_kernel<<<16384, 256, 0, stream>>>(qkvb, qb, cs,
                                           0.08838834764831845f * 1.4426950408889634f);
    rope_kernel<<<16384, 256, 0, stream>>>(qkvb + 2048, kb, cs, 1.0f);
    attn_kernel<<<dim3(32, 32), 256, 0, stream>>>(qb, kb, qkvb + 4096, ob, 6144);

    // O projection + residual (fp32 out)
    cast_f32_bf16_kernel<<<2048, 256, 0, stream>>>(wo, Wbuf, 524288);
    gemm256<0, 1><<<256, 512, 147456, stream>>>(ob, Wbuf, x2, x, 2048, 2048, 16);

    ln_kernel<<<4096, 256, 0, stream>>>(x2, ln2w, ln2b, hb);

    // MLP gate/up in two 4096-column halves (SiLU fused in epilogue)
    for (int h = 0; h < 2; ++h) {
        cast_f32_bf16_kernel<<<4096, 256, 0, stream>>>(wg + (size_t)h * 8388608, Wbuf, 1048576);
        cast_f32_bf16_kernel<<<4096, 256, 0, stream>>>(wu + (size_t)h * 8388608, Wbuf + 8388608, 1048576);
        gemm_gu256<<<1024, 512, 147456, stream>>>(hb, Wbuf, Wbuf + 8388608,
                                                  mb + h * 4096, 8192, 2048, 64);
    }

    // Down projection + residual -> fp32 d_out
    cast_f32_bf16_kernel<<<8192, 256, 0, stream>>>(wd, Wbuf, 2097152);
    gemm256<0, 1><<<256, 512, 147456, stream>>>(mb, Wbuf, (float*)d_out, x2, 2048, 8192, 16);
}